// Round 8
// baseline (342.770 us; speedup 1.0000x reference)
//
#include <hip/hip_runtime.h>
#include <math.h>

// Problem constants
#define BB 2
#define LL 1024
#define HIDD 1024
#define NH 4
#define DD 256
#define NCH 32
#define ROWS 2048
#define HROWS 8192

typedef long long i64;
typedef unsigned short u16t;
typedef unsigned int u32t;
typedef __attribute__((ext_vector_type(8))) short short8;
typedef __attribute__((ext_vector_type(4))) float f32x4;
#define MFMA_BF16(a, b, c) __builtin_amdgcn_mfma_f32_16x16x32_bf16(a, b, c, 0, 0, 0)

__device__ __forceinline__ float sigmoidf_(float x) { return 1.0f / (1.0f + expf(-x)); }

__device__ __forceinline__ u16t f2bf(float f) {
  u32t u = __float_as_uint(f);
  u = u + 0x7FFFu + ((u >> 16) & 1u);
  return (u16t)(u >> 16);
}
__device__ __forceinline__ u32t pk2(u16t a, u16t b) { return (u32t)a | ((u32t)b << 16); }

// HW packed f32->bf16 RNE convert (gfx950): 1 instr vs 6-op bit-trick pair.
__device__ __forceinline__ u32t cvt_pk_bf16(float lo, float hi) {
  u32t r;
  asm("v_cvt_pk_bf16_f32 %0, %1, %2" : "=v"(r) : "v"(lo), "v"(hi));
  return r;
}

// counted-wait barrier: drain only LDS ops, keep global loads in flight.
__device__ __forceinline__ void barrier_lds_only() {
  asm volatile("s_waitcnt lgkmcnt(0)" ::: "memory");
  __builtin_amdgcn_s_barrier();
  asm volatile("" ::: "memory");
}

// ---------------- block reduction helper (blockDim == 256) ----------------
template<int N>
__device__ __forceinline__ void block_reduce_sum(float* v, float* scratch) {
  int lane = threadIdx.x & 63, wid = threadIdx.x >> 6;
#pragma unroll
  for (int i = 0; i < N; i++) {
    float x = v[i];
#pragma unroll
    for (int off = 1; off < 64; off <<= 1) x += __shfl_xor(x, off);
    if (lane == 0) scratch[wid * N + i] = x;
  }
  __syncthreads();
#pragma unroll
  for (int i = 0; i < N; i++)
    v[i] = scratch[i] + scratch[N + i] + scratch[2 * N + i] + scratch[3 * N + i];
  __syncthreads();
}

// ---------------- transpose+cast body: fp32 [K][N] -> bf16 [N][K], one 32x32 tile ----------------
__device__ __forceinline__ void transcast_body(
    const float* __restrict__ in, int ldin, u16t* __restrict__ out, int ldout,
    int nbi, int kbi, float (*tile)[33]) {
  int tx = threadIdx.x & 31, ty = threadIdx.x >> 5;
  int nb = nbi * 32, kb = kbi * 32;
#pragma unroll
  for (int r = 0; r < 4; r++)
    tile[ty + r * 8][tx] = in[(i64)(kb + ty + r * 8) * ldin + nb + tx];
  __syncthreads();
#pragma unroll
  for (int r = 0; r < 4; r++)
    out[(i64)(nb + ty + r * 8) * ldout + kb + tx] = f2bf(tile[tx][ty + r * 8]);
}

// ---------------- prep (step 1): WqkvT(3072) + xbf(2048) + beta(2048) ----------------
// beta folded in: reads only x,Wb (available at step 1); betab consumed at step 4.
__global__ __launch_bounds__(256) void prep_kernel(
    const float* __restrict__ Wq, const float* __restrict__ Wk, const float* __restrict__ Wv,
    const float* __restrict__ x, const float* __restrict__ Wb,
    u16t* __restrict__ WqkvT, u16t* __restrict__ xbf, float* __restrict__ betab) {
  __shared__ float tile[32][33];
  int blk = blockIdx.x, t = threadIdx.x;
  if (blk < 3072) {
    int m = blk >> 10, bi = blk & 1023;
    const float* in = m == 0 ? Wq : m == 1 ? Wk : Wv;
    transcast_body(in, 1024, WqkvT + (i64)m * 1024 * 1024, 1024, bi & 31, bi >> 5, tile);
  } else if (blk < 5120) {
    i64 e = ((i64)(blk - 3072) * 256 + t) * 4;
    float4 v = *(const float4*)(x + e);
    uint2 o;
    o.x = pk2(f2bf(v.x), f2bf(v.y));
    o.y = pk2(f2bf(v.z), f2bf(v.w));
    *(uint2*)(xbf + e) = o;
  } else {
    int row = blk - 5120;
    float a[4] = {0, 0, 0, 0};
    for (int c = t; c < 1024; c += 256) {
      float xv = x[(i64)row * 1024 + c];
      float4 wv = *(const float4*)(Wb + c * 4);
      a[0] += xv * wv.x; a[1] += xv * wv.y; a[2] += xv * wv.z; a[3] += xv * wv.w;
    }
    block_reduce_sum<4>(a, (float*)tile);
    if (t == 0) {
#pragma unroll
      for (int g = 0; g < 4; g++) betab[row * 4 + g] = sigmoidf_(a[g]);
    }
  }
}

// ---------------- bf16 MFMA GEMM body: A[M][K], B[N][K] -> C[M][N] fp32 ----------------
__device__ __forceinline__ void gemm_bt_body(
    const u16t* __restrict__ A, const u16t* __restrict__ B,
    float* __restrict__ C, int K, int ldc, int n0, int m0,
    u16t* As, u16t* Bs) {
  int t = threadIdx.x;
  int w = t >> 6, lane = t & 63;
  int l15 = lane & 15, quad = lane >> 4;
  int wm = (w & 1) * 64, wn = (w >> 1) * 64;
  f32x4 acc[4][4] = {};
  int srow = t >> 1, shalf = (t & 1) * 16;
  const u16t* Ag = A + (i64)(m0 + srow) * K + shalf;
  const u16t* Bg = B + (i64)(n0 + srow) * K + shalf;
  for (int k0 = 0; k0 < K; k0 += 32) {
    *(uint4*)&As[srow * 40 + shalf] = *(const uint4*)(Ag + k0);
    *(uint4*)&As[srow * 40 + shalf + 8] = *(const uint4*)(Ag + k0 + 8);
    *(uint4*)&Bs[srow * 40 + shalf] = *(const uint4*)(Bg + k0);
    *(uint4*)&Bs[srow * 40 + shalf + 8] = *(const uint4*)(Bg + k0 + 8);
    __syncthreads();
    short8 a[4], b[4];
#pragma unroll
    for (int mt = 0; mt < 4; mt++)
      a[mt] = *(const short8*)&As[(wm + mt * 16 + l15) * 40 + quad * 8];
#pragma unroll
    for (int nt = 0; nt < 4; nt++)
      b[nt] = *(const short8*)&Bs[(wn + nt * 16 + l15) * 40 + quad * 8];
#pragma unroll
    for (int mt = 0; mt < 4; mt++)
#pragma unroll
      for (int nt = 0; nt < 4; nt++)
        acc[mt][nt] = MFMA_BF16(a[mt], b[nt], acc[mt][nt]);
    __syncthreads();
  }
#pragma unroll
  for (int mt = 0; mt < 4; mt++) {
    int r0 = m0 + wm + mt * 16 + quad * 4;
#pragma unroll
    for (int nt = 0; nt < 4; nt++) {
      int cc = n0 + wn + nt * 16 + l15;
#pragma unroll
      for (int rg = 0; rg < 4; rg++)
        C[(i64)(r0 + rg) * ldc + cc] = acc[mt][nt][rg];
    }
  }
}

__global__ __launch_bounds__(256) void gemm_bt_kernel(
    const u16t* __restrict__ A, const u16t* __restrict__ B,
    float* __restrict__ C, int K, int ldc) {
  __shared__ u16t As[128 * 40];
  __shared__ u16t Bs[128 * 40];
  gemm_bt_body(A, B, C, K, ldc, blockIdx.x * 128, blockIdx.y * 128, As, Bs);
}

// ---------------- fused causal depthwise conv (K=4) + silu, VECTORIZED x4 ----------------
__global__ __launch_bounds__(256) void conv_silu3_kernel(
    const float* __restrict__ pre, const float* __restrict__ qw,
    const float* __restrict__ kw, const float* __restrict__ vw,
    float* __restrict__ qo, float* __restrict__ ko, float* __restrict__ vo,
    u16t* __restrict__ brcat) {
  int seg = blockIdx.x >> 11;          // 3 segs x 2048 rows
  int row = blockIdx.x & 2047;         // b*1024 + l
  int l = row & 1023;
  int c = threadIdx.x * 4;
  const float* w = seg == 0 ? qw : seg == 1 ? kw : vw;
  float* out = seg == 0 ? qo : seg == 1 ? ko : vo;
  float4 w0 = *(const float4*)(w + (i64)(c + 0) * 4);
  float4 w1 = *(const float4*)(w + (i64)(c + 1) * 4);
  float4 w2 = *(const float4*)(w + (i64)(c + 2) * 4);
  float4 w3 = *(const float4*)(w + (i64)(c + 3) * 4);
  const float* base = pre + (i64)row * 3072 + (seg << 10) + c;
  float4 x0 = *(const float4*)(base);
  float4 acc;
  acc.x = w0.w * x0.x; acc.y = w1.w * x0.y; acc.z = w2.w * x0.z; acc.w = w3.w * x0.w;
  if (l >= 1) {
    float4 xm = *(const float4*)(base - 3072);
    acc.x += w0.z * xm.x; acc.y += w1.z * xm.y; acc.z += w2.z * xm.z; acc.w += w3.z * xm.w;
  }
  if (l >= 2) {
    float4 xm = *(const float4*)(base - 2 * 3072);
    acc.x += w0.y * xm.x; acc.y += w1.y * xm.y; acc.z += w2.y * xm.z; acc.w += w3.y * xm.w;
  }
  if (l >= 3) {
    float4 xm = *(const float4*)(base - 3 * 3072);
    acc.x += w0.x * xm.x; acc.y += w1.x * xm.y; acc.z += w2.x * xm.z; acc.w += w3.x * xm.w;
  }
  float4 r;
  r.x = acc.x * sigmoidf_(acc.x);
  r.y = acc.y * sigmoidf_(acc.y);
  r.z = acc.z * sigmoidf_(acc.z);
  r.w = acc.w * sigmoidf_(acc.w);
  *(float4*)(out + (i64)row * 1024 + c) = r;
  if (seg == 2) {
    uint2 o;
    o.x = cvt_pk_bf16(r.x, r.y);
    o.y = cvt_pk_bf16(r.z, r.w);
    *(uint2*)(brcat + ((i64)row * 4 + (c >> 8)) * 1024 + 768 + (c & 255)) = o;
  }
}

// ---------------- preprocess: WAVE-PER-ROW, float4 (G13) ----------------
__global__ __launch_bounds__(256) void preprocess_kernel(
    const float* __restrict__ q, const float* __restrict__ k, const float* __restrict__ v,
    const float* __restrict__ beta, float* __restrict__ qn, float* __restrict__ kn,
    float* __restrict__ vb, float* __restrict__ kb, u16t* __restrict__ qnbf) {
  int t = threadIdx.x, lane = t & 63, wv = t >> 6;
  int row = blockIdx.x * 4 + wv;       // (b*1024+l)*4+h
  i64 base = (i64)row * 256 + lane * 4;
  float4 q4 = *(const float4*)(q + base);
  float4 k4 = *(const float4*)(k + base);
  float4 v4 = *(const float4*)(v + base);
  float s2[2];
  s2[0] = q4.x * q4.x + q4.y * q4.y + q4.z * q4.z + q4.w * q4.w;
  s2[1] = k4.x * k4.x + k4.y * k4.y + k4.z * k4.z + k4.w * k4.w;
#pragma unroll
  for (int off = 1; off < 64; off <<= 1) {
    s2[0] += __shfl_xor(s2[0], off);
    s2[1] += __shfl_xor(s2[1], off);
  }
  float qi = rsqrtf(s2[0] + 1e-6f), ki = rsqrtf(s2[1] + 1e-6f);
  float bet = beta[row];
  float4 qn4, kn4, vb4, kb4;
  qn4.x = q4.x * qi; qn4.y = q4.y * qi; qn4.z = q4.z * qi; qn4.w = q4.w * qi;
  kn4.x = k4.x * ki; kn4.y = k4.y * ki; kn4.z = k4.z * ki; kn4.w = k4.w * ki;
  vb4.x = v4.x * bet; vb4.y = v4.y * bet; vb4.z = v4.z * bet; vb4.w = v4.w * bet;
  kb4.x = kn4.x * bet; kb4.y = kn4.y * bet; kb4.z = kn4.z * bet; kb4.w = kn4.w * bet;
  *(float4*)(qn + base) = qn4;
  *(float4*)(kn + base) = kn4;
  *(float4*)(vb + base) = vb4;
  *(float4*)(kb + base) = kb4;
  int b = row >> 12, l = (row >> 2) & 1023, h = row & 3;
  uint2 o;
  o.x = cvt_pk_bf16(qn4.x, qn4.y);
  o.y = cvt_pk_bf16(qn4.z, qn4.w);
  *(uint2*)(qnbf + ((i64)(b * 4 + h) * 1024 + l) * 256 + lane * 4) = o;
}

// ---------------- phaseA2: phaseA(256) + W1/Wo transposes(2048) + wsum(24) ----
// Transposes now target the dead-qkv_pre region (no vb alias) so they can run
// here, hiding phaseA's 1-block/CU latency-bound UT recurrence under 2072
// independent memory blocks.
__global__ __launch_bounds__(256) void phaseA2_kernel(
    const float* __restrict__ qn, const float* __restrict__ kn,
    const float* __restrict__ vb, const float* __restrict__ kb,
    float* __restrict__ u_g, u16t* __restrict__ w_bf, u16t* __restrict__ attn_bf,
    u16t* __restrict__ knT,
    const float* __restrict__ gW1, const float* __restrict__ Wo,
    u16t* __restrict__ W1hT, u16t* __restrict__ W1bT, u16t* __restrict__ WoT,
    float* __restrict__ wsum) {
  __shared__ __attribute__((aligned(16))) char smem[37376];
  int blk = blockIdx.x, t = threadIdx.x;
  if (blk < 256) {
    float (*KN)[260] = (float(*)[260])smem;          // 33280 B
    float (*Ms)[32] = (float(*)[32])(smem + 33280);  // 4096 B
    int i = blk & 31, bh = blk >> 5;
    int rbase = ((bh >> 2) * LL + i * 32) * NH + (bh & 3);
    i64 bhn = blk;
#pragma unroll
    for (int ii = 0; ii < 8; ii++) {
      int fid = t + ii * 256;
      int c = fid >> 6, dq = (fid & 63) << 2;
      *(float4*)&KN[c][dq] = *(const float4*)(kn + (i64)(rbase + c * NH) * 256 + dq);
    }
    __syncthreads();
    int c = t >> 3, e0 = (t & 7) * 4;
    const float* kbp = kb + (i64)(rbase + c * NH) * 256;
    const float* qp = qn + (i64)(rbase + c * NH) * 256;
    float am[4] = {0, 0, 0, 0}, aa[4] = {0, 0, 0, 0};
    for (int d = 0; d < 256; d += 4) {
      float4 kv = *(const float4*)(kbp + d);
      float4 qv = *(const float4*)(qp + d);
#pragma unroll
      for (int z = 0; z < 4; z++) {
        float4 nv = *(const float4*)&KN[e0 + z][d];
        am[z] += kv.x * nv.x + kv.y * nv.y + kv.z * nv.z + kv.w * nv.w;
        aa[z] += qv.x * nv.x + qv.y * nv.y + qv.z * nv.z + qv.w * nv.w;
      }
    }
    {
      uint2 o;
      u16t a0 = (e0 + 0 <= c) ? f2bf(aa[0]) : 0;
      u16t a1 = (e0 + 1 <= c) ? f2bf(aa[1]) : 0;
      u16t a2 = (e0 + 2 <= c) ? f2bf(aa[2]) : 0;
      u16t a3 = (e0 + 3 <= c) ? f2bf(aa[3]) : 0;
      o.x = pk2(a0, a1); o.y = pk2(a2, a3);
      *(uint2*)(attn_bf + bhn * 1024 + c * 32 + e0) = o;
    }
#pragma unroll
    for (int z = 0; z < 4; z++) {
      int e = e0 + z;
      Ms[c][e] = (e < c) ? am[z] : 0.0f;
    }
    __syncthreads();
    float uc[32], wc[32];
#pragma unroll
    for (int cc = 0; cc < 32; cc++) {
      float uval = vb[(i64)(rbase + cc * NH) * 256 + t];
      float wval = kb[(i64)(rbase + cc * NH) * 256 + t];
#pragma unroll
      for (int c2 = 0; c2 < cc; c2++) {
        float m = Ms[cc][c2];
        uval -= m * uc[c2];
        wval -= m * wc[c2];
      }
      uc[cc] = uval; wc[cc] = wval;
      u_g[(bhn * 32 + cc) * 256 + t] = uval;
      w_bf[(bhn * 32 + cc) * 256 + t] = f2bf(-wval);
    }
    int d = t;
    u16t o[32];
#pragma unroll
    for (int cc = 0; cc < 32; cc++) o[cc] = f2bf(KN[cc][d]);
#pragma unroll
    for (int z = 0; z < 4; z++) {
      uint4 vv;
      vv.x = pk2(o[z * 8 + 0], o[z * 8 + 1]);
      vv.y = pk2(o[z * 8 + 2], o[z * 8 + 3]);
      vv.z = pk2(o[z * 8 + 4], o[z * 8 + 5]);
      vv.w = pk2(o[z * 8 + 6], o[z * 8 + 7]);
      *(uint4*)(knT + (bhn * 256 + d) * 32 + z * 8) = vv;
    }
  } else if (blk < 2304) {
    float (*tile)[33] = (float(*)[33])smem;
    int pb = blk - 256;
    if (pb < 1024) {
      int which = pb >> 9, bi = pb & 511;
      const float* in = gW1 + (which ? (i64)4096 * 512 : 0);
      transcast_body(in, 512, which ? W1bT : W1hT, 1024, bi & 15, bi >> 4, tile);
    } else {
      int bi = pb - 1024;
      transcast_body(Wo, 1024, WoT, 1024, bi & 31, bi >> 5, tile);
    }
  } else {
    int bi = blk - 2304;         // 24 blocks: 12 stats x 2 col-halves
    int s12 = bi >> 1, col = (bi & 1) * 256 + t;
    const float* p = gW1 + (i64)(1024 + s12 * 256) * 512 + col;
    float acc = 0.0f;
    for (int r = 0; r < 256; r++) acc += p[(i64)r * 512];
    wsum[s12 * 512 + col] = acc;
  }
}

// ---------------- delta scan body (verbatim passing version) ----------------
#define SROW 264
struct ScanBuf {
  short8 m8[8];
  f32x4 uc4;
  short8 af;
  short8 kf[4];
};

__device__ void delta_scan_body(
    int blk,
    const u16t* __restrict__ wbf, const u16t* __restrict__ knT,
    const float* __restrict__ u_g, const u16t* __restrict__ qnbf,
    const u16t* __restrict__ attnbf,
    float* __restrict__ dlt, u16t* __restrict__ brcat,
    u16t* Sbf, u16t* Ubf) {
  int t = threadIdx.x, w = t >> 6, lane = t & 63;
  int l15 = lane & 15, quad = lane >> 4;
  int bh = blk & 7, jb = blk >> 3, j0 = jb * 16;
  int b_ = bh >> 2, h_ = bh & 3;
  bool isU = (w < 2);
  int wc = isU ? w : (w - 2);
  for (int idx = t; idx < 16 * SROW; idx += 256) Sbf[idx] = 0;
  f32x4 accS[4] = {};
  __syncthreads();
  __builtin_amdgcn_s_setprio(1);

  auto load_chunk = [&](int i, ScanBuf& B) {
    i64 bhn = (i64)bh * 32 + i;
    const u16t* mbase = isU
        ? wbf + (bhn * 32 + wc * 16 + l15) * 256 + quad * 8
        : qnbf + ((i64)bh * 1024 + i * 32 + wc * 16 + l15) * 256 + quad * 8;
#pragma unroll
    for (int kd = 0; kd < 8; kd++) B.m8[kd] = *(const short8*)(mbase + kd * 32);
    if (isU) {
      int cm = wc * 16 + quad * 4;
#pragma unroll
      for (int r = 0; r < 4; r++)
        B.uc4[r] = u_g[(bhn * 32 + cm + r) * 256 + j0 + l15];
    } else {
      B.af = *(const short8*)(attnbf + bhn * 1024 + (wc * 16 + l15) * 32 + quad * 8);
    }
#pragma unroll
    for (int dt = 0; dt < 4; dt++)
      B.kf[dt] = *(const short8*)(knT + (bhn * 256 + w * 64 + dt * 16 + l15) * 32 + quad * 8);
  };

  auto process = [&](int i, ScanBuf& B) {
    f32x4 zero = {};
    f32x4 ca = isU ? B.uc4 : zero;
    f32x4 cb = zero;
#pragma unroll
    for (int kd = 0; kd < 4; kd++) {
      short8 sfa = *(const short8*)&Sbf[l15 * SROW + kd * 32 + quad * 8];
      short8 sfb = *(const short8*)&Sbf[l15 * SROW + (kd + 4) * 32 + quad * 8];
      ca = MFMA_BF16(B.m8[kd], sfa, ca);
      cb = MFMA_BF16(B.m8[kd + 4], sfb, cb);
    }
    f32x4 cacc;
#pragma unroll
    for (int r = 0; r < 4; r++) cacc[r] = ca[r] + cb[r];
    if (isU) {
      int cm = wc * 16 + quad * 4;
      uint2 o;
      o.x = cvt_pk_bf16(cacc[0], cacc[1]);
      o.y = cvt_pk_bf16(cacc[2], cacc[3]);
      *(uint2*)&Ubf[l15 * 40 + cm] = o;
    }
    barrier_lds_only();
    short8 bu = *(const short8*)&Ubf[l15 * 40 + quad * 8];
    if (!isU) {
      cacc = MFMA_BF16(B.af, bu, cacc);
#pragma unroll
      for (int rg = 0; rg < 4; rg++) {
        int l = i * 32 + wc * 16 + quad * 4 + rg;
        i64 row = ((i64)b_ * 1024 + l) * 4 + h_;
        dlt[row * 256 + j0 + l15] = cacc[rg];
        brcat[row * 1024 + 512 + j0 + l15] = f2bf(cacc[rg]);
      }
    }
#pragma unroll
    for (int dt = 0; dt < 4; dt++) accS[dt] = MFMA_BF16(B.kf[dt], bu, accS[dt]);
#pragma unroll
    for (int dt = 0; dt < 4; dt++) {
      uint2 o;
      o.x = cvt_pk_bf16(accS[dt][0], accS[dt][1]);
      o.y = cvt_pk_bf16(accS[dt][2], accS[dt][3]);
      *(uint2*)&Sbf[l15 * SROW + w * 64 + dt * 16 + quad * 4] = o;
    }
    barrier_lds_only();
  };

  ScanBuf b0, b1;
  load_chunk(0, b0);
#pragma unroll 1
  for (int ii = 0; ii < 16; ii++) {
    int i = ii * 2;
    load_chunk(i + 1, b1);
    process(i, b0);
    if (ii < 15) load_chunk(i + 2, b0);
    process(i + 1, b1);
  }
  __builtin_amdgcn_s_setprio(0);
}

// ---------------- FIR body ----------------
__device__ void fir2_body(
    int blk, const float* __restrict__ v,
    const float* __restrict__ f_s, const float* __restrict__ f_l,
    float* __restrict__ fs, float* __restrict__ fl, u16t* __restrict__ brcat) {
  int t = threadIdx.x;
  int b = blk >> 8, h = (blk >> 6) & 3, lc = blk & 63;
  int l0 = lc * 16;
  float flw[31], fsw[3];
  const float* flp = f_l + ((i64)h * 256 + t) * 31;
#pragma unroll
  for (int j = 0; j < 31; j++) flw[j] = flp[j];
  const float* fsp = f_s + ((i64)h * 256 + t) * 3;
#pragma unroll
  for (int j = 0; j < 3; j++) fsw[j] = fsp[j];
  float win[46];
#pragma unroll
  for (int r = 0; r < 46; r++) {
    int l = l0 - 30 + r;
    win[r] = (l >= 0) ? v[(((i64)b * 1024 + l) * 4 + h) * 256 + t] : 0.0f;
  }
#pragma unroll
  for (int i = 0; i < 16; i++) {
    float al = 0.0f;
#pragma unroll
    for (int j = 0; j < 31; j++) al += flw[j] * win[i + j];
    float as = fsw[0] * win[i + 28] + fsw[1] * win[i + 29] + fsw[2] * win[i + 30];
    i64 row = ((i64)b * 1024 + (l0 + i)) * 4 + h;
    fs[row * 256 + t] = as;
    fl[row * 256 + t] = al;
    brcat[row * 1024 + t] = f2bf(as);
    brcat[row * 1024 + 256 + t] = f2bf(al);
  }
}

// ---------------- mega5: scan(128) + fir(512) + hbase gemm(64) ----------------
// hbase GEMM (long-running MFMA blocks) backfills as scan cover; its deps
// (xbf from step 1, W1hT from step 5) are both complete.
__global__ __launch_bounds__(256) void mega5_kernel(
    const u16t* __restrict__ wbf, const u16t* __restrict__ knT,
    const float* __restrict__ u_g, const u16t* __restrict__ qnbf,
    const u16t* __restrict__ attnbf, float* __restrict__ dlt, u16t* __restrict__ brcat,
    const float* __restrict__ vbuf, const float* __restrict__ firs,
    const float* __restrict__ firl, float* __restrict__ fs, float* __restrict__ fl,
    const u16t* __restrict__ xbf, const u16t* __restrict__ W1hT,
    float* __restrict__ hbase) {
  __shared__ __attribute__((aligned(16))) char smem[20480];
  int blk = blockIdx.x;
  if (blk < 128) {
    u16t* Sbf = (u16t*)smem;
    u16t* Ubf = Sbf + 16 * SROW;
    delta_scan_body(blk, wbf, knT, u_g, qnbf, attnbf, dlt, brcat, Sbf, Ubf);
  } else if (blk < 640) {
    fir2_body(blk - 128, vbuf, firs, firl, fs, fl, brcat);
  } else {
    int bi = blk - 640;
    u16t* As = (u16t*)smem;
    u16t* Bs = As + 128 * 40;
    gemm_bt_body(xbf, W1hT, hbase, 1024, 512, (bi & 3) * 128, (bi >> 2) * 128, As, Bs);
  }
}

// ---------------- gate MLP tail + mix + RMS norm: WAVE-PER-ROW ----------------
__global__ __launch_bounds__(256) void gatemix_kernel(
    const float* __restrict__ hbase, const float* __restrict__ brW,
    const float* __restrict__ wsum,
    const float* __restrict__ gb1, const float* __restrict__ gW2,
    const float* __restrict__ gb2, const float* __restrict__ temp,
    const float* __restrict__ epsf,
    const float* __restrict__ fs, const float* __restrict__ fl,
    const float* __restrict__ dlt, const float* __restrict__ v,
    const float* __restrict__ onw, u16t* __restrict__ out) {
  int t = threadIdx.x, lane = t & 63, wv = t >> 6;
  int row = blockIdx.x * 4 + wv;      // (b*1024+l)*4+h
  int bl = row >> 2, h = row & 3;
  i64 base = (i64)row * 256 + lane * 4;
  float4 vfs = *(const float4*)(fs + base);
  float4 vfl = *(const float4*)(fl + base);
  float4 vdl = *(const float4*)(dlt + base);
  float4 vvv = *(const float4*)(v + base);
  float r8[8];
  r8[0] = vfs.x + vfs.y + vfs.z + vfs.w;
  r8[1] = vfs.x * vfs.x + vfs.y * vfs.y + vfs.z * vfs.z + vfs.w * vfs.w;
  r8[2] = vfl.x + vfl.y + vfl.z + vfl.w;
  r8[3] = vfl.x * vfl.x + vfl.y * vfl.y + vfl.z * vfl.z + vfl.w * vfl.w;
  r8[4] = vdl.x + vdl.y + vdl.z + vdl.w;
  r8[5] = vdl.x * vdl.x + vdl.y * vdl.y + vdl.z * vdl.z + vdl.w * vdl.w;
  r8[6] = vvv.x + vvv.y + vvv.z + vvv.w;
  r8[7] = vvv.x * vvv.x + vvv.y * vvv.y + vvv.z * vvv.z + vvv.w * vvv.w;
#pragma unroll
  for (int off = 1; off < 64; off <<= 1) {
#pragma unroll
    for (int i = 0; i < 8; i++) r8[i] += __shfl_xor(r8[i], off);
  }
  float m4[4];
  m4[0] = fmaxf(fmaxf(vfs.x, vfs.y), fmaxf(vfs.z, vfs.w));
  m4[1] = fmaxf(fmaxf(vfl.x, vfl.y), fmaxf(vfl.z, vfl.w));
  m4[2] = fmaxf(fmaxf(vdl.x, vdl.y), fmaxf(vdl.z, vdl.w));
  m4[3] = fmaxf(fmaxf(vvv.x, vvv.y), fmaxf(vvv.z, vvv.w));
#pragma unroll
  for (int off = 1; off < 64; off <<= 1) {
#pragma unroll
    for (int i = 0; i < 4; i++) m4[i] = fmaxf(m4[i], __shfl_xor(m4[i], off));
  }
  float st[12];
#pragma unroll
  for (int p = 0; p < 4; p++) {
    st[p * 3 + 0] = r8[p * 2] * (1.0f / 256.0f);
    st[p * 3 + 1] = sqrtf(fmaxf(r8[p * 2 + 1] * (1.0f / 256.0f), 1e-8f));
    st[p * 3 + 2] = m4[p];
  }
  float lg[4] = {0, 0, 0, 0};
#pragma unroll
  for (int jj = 0; jj < 8; jj++) {
    int o = jj * 64 + lane;
    float hm = hbase[(i64)bl * 512 + o] + brW[(i64)row * 512 + o] + gb1[o];
#pragma unroll
    for (int s = 0; s < 12; s++) hm += st[s] * wsum[s * 512 + o];
    float ge = 0.5f * hm * (1.0f + erff(hm * 0.70710678118654752f));
    float4 w2 = *(const float4*)(gW2 + o * 4);
    lg[0] += ge * w2.x; lg[1] += ge * w2.y; lg[2] += ge * w2.z; lg[3] += ge * w2.w;
  }
#pragma unroll
  for (int off = 1; off < 64; off <<= 1) {
#pragma unroll
    for (int i = 0; i < 4; i++) lg[i] += __shfl_xor(lg[i], off);
  }
  float tt = fminf(fmaxf(temp[h], 0.2f), 10.0f);
  float l0 = (lg[0] + gb2[0]) / tt;
  float l1 = (lg[1] + gb2[1]) / tt;
  float l2 = (lg[2] + gb2[2]) / tt;
  float l3 = (lg[3] + gb2[3]) / tt;
  float m = fmaxf(fmaxf(l0, l1), fmaxf(l2, l3));
  float e0 = expf(l0 - m), e1 = expf(l1 - m), e2 = expf(l2 - m), e3 = expf(l3 - m);
  float ssum = e0 + e1 + e2 + e3;
  float w0 = e0 / ssum, w1 = e1 / ssum, w2 = e2 / ssum, w3 = e3 / ssum;
  w0 = fmaxf(w0, fminf(fmaxf(epsf[h * 4 + 0], 1e-7f), 0.1f));
  w1 = fmaxf(w1, fminf(fmaxf(epsf[h * 4 + 1], 1e-7f), 0.1f));
  w2 = fmaxf(w2, fminf(fmaxf(epsf[h * 4 + 2], 1e-7f), 0.1f));
  w3 = fmaxf(w3, fminf(fmaxf(epsf[h * 4 + 3], 1e-7f), 0.1f));
  float s2 = w0 + w1 + w2 + w3;
  float g0 = w0 / s2, g1 = w1 / s2, g2 = w2 / s2, g3 = w3 / s2;
  float4 o4;
  o4.x = g0 * vfs.x + g1 * vfl.x + g2 * vdl.x + g3 * vvv.x;
  o4.y = g0 * vfs.y + g1 * vfl.y + g2 * vdl.y + g3 * vvv.y;
  o4.z = g0 * vfs.z + g1 * vfl.z + g2 * vdl.z + g3 * vvv.z;
  o4.w = g0 * vfs.w + g1 * vfl.w + g2 * vdl.w + g3 * vvv.w;
  float ss = o4.x * o4.x + o4.y * o4.y + o4.z * o4.z + o4.w * o4.w;
#pragma unroll
  for (int off = 1; off < 64; off <<= 1) ss += __shfl_xor(ss, off);
  float scale = rsqrtf(ss * (1.0f / 256.0f) + 1e-5f);
  float4 ow4 = *(const float4*)(onw + lane * 4);
  uint2 ow;
  ow.x = cvt_pk_bf16(o4.x * scale * ow4.x, o4.y * scale * ow4.y);
  ow.y = cvt_pk_bf16(o4.z * scale * ow4.z, o4.w * scale * ow4.w);
  *(uint2*)(out + (i64)bl * 1024 + h * 256 + lane * 4) = ow;
}

extern "C" void kernel_launch(void* const* d_in, const int* in_sizes, int n_in,
                              void* d_out, int out_size, void* d_ws, size_t ws_size,
                              hipStream_t stream) {
  (void)in_sizes; (void)n_in; (void)out_size; (void)ws_size;
  const float* x    = (const float*)d_in[0];
  const float* Wq   = (const float*)d_in[1];
  const float* Wk   = (const float*)d_in[2];
  const float* Wv   = (const float*)d_in[3];
  const float* Wb   = (const float*)d_in[4];
  const float* qcw  = (const float*)d_in[5];
  const float* kcw  = (const float*)d_in[6];
  const float* vcw  = (const float*)d_in[7];
  const float* gW1  = (const float*)d_in[8];
  const float* gb1  = (const float*)d_in[9];
  const float* gW2  = (const float*)d_in[10];
  const float* gb2  = (const float*)d_in[11];
  const float* temp = (const float*)d_in[12];
  const float* epsf = (const float*)d_in[13];
  const float* onw  = (const float*)d_in[14];
  const float* Wo   = (const float*)d_in[15];
  const float* firs = (const float*)d_in[16];
  const float* firl = (const float*)d_in[17];
  float* out = (float*)d_out;

  float* ws = (float*)d_ws;
  // ---- workspace map (float offsets) ----
  // W1hT/W1bT/WoT now live in the dead-qkv_pre slice [5242880, 6291456):
  //   qkv_pre [0,6291456) dead after conv (step 3); transposes written step 5;
  //   hbase [4194304,5242880) step 6; branchW [0,4194304) step 7 — disjoint.
  float* qkv_pre  = ws + 0;                       // 2048*3072 fp32 (dead after conv)
  float* branchW  = ws + 0;                       // 8192*512 fp32 (step 7+)
  float* hbase    = ws + 4194304;                 // 2048*512 fp32 (step 6+)
  u16t*  W1hT     = (u16t*)(ws + 5242880);        // 512x1024 bf16 (step 5+)
  u16t*  W1bT     = (u16t*)(ws + 5505024);        // 512x1024 bf16
  u16t*  WoT      = (u16t*)(ws + 5767168);        // 1024x1024 bf16
  u16t*  brcat    = (u16t*)(ws + 6291456);        // 8192*1024 bf16
  float* qbuf     = ws + 10485760; float* qn = qbuf;
  float* kbuf     = ws + 12582912; float* kn = kbuf;
  float* vbuf     = ws + 14680064;
  float* vb       = ws + 16777216;                // dead after phaseA2
  u16t*  omix_bf  = (u16t*)(ws + 16777216);       // gatemix+ (2048*1024 bf16)
  float* kb       = ws + 18874368;                // dead after phaseA2
  float* dlt      = ws + 18874368;                // scan output
  float* u_g      = ws + 20971520;
  u16t*  w_bf     = (u16t*)(ws + 23068672);
  u16t*  qn_bf    = (u16t*)(ws + 24117248);
  u16t*  knT      = (u16t*)(ws + 25165824);
  u16t*  attn_bf  = (u16t*)(ws + 26214400);
  float* fs       = ws + 26345472;
  float* fl       = ws + 28442624;
  u16t*  xbf      = (u16t*)(ws + 30539776);
  u16t*  WqkvT    = (u16t*)(ws + 31588352);
  float* betab    = ws + 33161216;                // 8192 fp32
  float* wsum     = ws + 33267712;

  // 1) prep: QKV weight transpose + x cast + beta (all read-only inputs)
  prep_kernel<<<7168, 256, 0, stream>>>(Wq, Wk, Wv, x, Wb, WqkvT, xbf, betab);
  // 2) QKV GEMM
  gemm_bt_kernel<<<dim3(24, 16), 256, 0, stream>>>(xbf, WqkvT, qkv_pre, 1024, 3072);
  // 3) conv+silu vectorized x4 (v also -> brcat col 768); kills qkv_pre
  conv_silu3_kernel<<<6144, 256, 0, stream>>>(qkv_pre, qcw, kcw, vcw, qbuf, kbuf, vbuf, brcat);
  // 4) preprocess (wave-per-row, float4)
  preprocess_kernel<<<2048, 256, 0, stream>>>(qbuf, kbuf, vbuf, betab, qn, kn, vb, kb, qn_bf);
  // 5) phaseA2: UT-transform + W1/Wo transposes (into dead qkv_pre) + wsum
  phaseA2_kernel<<<2328, 256, 0, stream>>>(qn, kn, vb, kb, u_g, w_bf, attn_bf, knT,
                                           gW1, Wo, W1hT, W1bT, WoT, wsum);
  // 6) mega5: scan + FIR + hbase GEMM (scan covered by FIR + long GEMM blocks)
  mega5_kernel<<<704, 256, 0, stream>>>(w_bf, knT, u_g, qn_bf, attn_bf, dlt, brcat,
                                        vbuf, firs, firl, fs, fl,
                                        xbf, W1hT, hbase);
  // 7) branchW GEMM
  gemm_bt_kernel<<<dim3(4, 64), 256, 0, stream>>>(brcat, W1bT, branchW, 1024, 512);
  // 8) gate tail + mix + RMS (wave-per-row, no barriers)
  gatemix_kernel<<<2048, 256, 0, stream>>>(hbase, branchW, wsum, gb1, gW2, gb2,
                                           temp, epsf, fs, fl, dlt, vbuf, onw, omix_bf);
  // 9) final projection
  gemm_bt_kernel<<<dim3(8, 16), 256, 0, stream>>>(omix_bf, WoT, out, 1024, 1024);
}

// Round 9
// 328.050 us; speedup vs baseline: 1.0449x; 1.0449x over previous
//
#include <hip/hip_runtime.h>
#include <math.h>

// Problem constants
#define BB 2
#define LL 1024
#define HIDD 1024
#define NH 4
#define DD 256
#define NCH 32
#define ROWS 2048
#define HROWS 8192

typedef long long i64;
typedef unsigned short u16t;
typedef unsigned int u32t;
typedef __attribute__((ext_vector_type(8))) short short8;
typedef __attribute__((ext_vector_type(4))) float f32x4;
#define MFMA_BF16(a, b, c) __builtin_amdgcn_mfma_f32_16x16x32_bf16(a, b, c, 0, 0, 0)

__device__ __forceinline__ float sigmoidf_(float x) { return 1.0f / (1.0f + expf(-x)); }

__device__ __forceinline__ u16t f2bf(float f) {
  u32t u = __float_as_uint(f);
  u = u + 0x7FFFu + ((u >> 16) & 1u);
  return (u16t)(u >> 16);
}
__device__ __forceinline__ u32t pk2(u16t a, u16t b) { return (u32t)a | ((u32t)b << 16); }

// HW packed f32->bf16 RNE convert (gfx950): 1 instr vs 6-op bit-trick pair.
__device__ __forceinline__ u32t cvt_pk_bf16(float lo, float hi) {
  u32t r;
  asm("v_cvt_pk_bf16_f32 %0, %1, %2" : "=v"(r) : "v"(lo), "v"(hi));
  return r;
}

// async global->LDS, 16B per lane. HW writes lane l's 16B at lds_base + l*16
// (wave-uniform LDS base, per-lane global src). Counted in vmcnt; the
// vmcnt(0) inside __syncthreads drains it.
__device__ __forceinline__ void async_load16(const u16t* g, u16t* l) {
  __builtin_amdgcn_global_load_lds(
      (const __attribute__((address_space(1))) u32t*)g,
      (__attribute__((address_space(3))) u32t*)l, 16, 0, 0);
}

// counted-wait barrier: drain only LDS ops, keep global loads in flight.
__device__ __forceinline__ void barrier_lds_only() {
  asm volatile("s_waitcnt lgkmcnt(0)" ::: "memory");
  __builtin_amdgcn_s_barrier();
  asm volatile("" ::: "memory");
}

// ---------------- block reduction helper (blockDim == 256) ----------------
template<int N>
__device__ __forceinline__ void block_reduce_sum(float* v, float* scratch) {
  int lane = threadIdx.x & 63, wid = threadIdx.x >> 6;
#pragma unroll
  for (int i = 0; i < N; i++) {
    float x = v[i];
#pragma unroll
    for (int off = 1; off < 64; off <<= 1) x += __shfl_xor(x, off);
    if (lane == 0) scratch[wid * N + i] = x;
  }
  __syncthreads();
#pragma unroll
  for (int i = 0; i < N; i++)
    v[i] = scratch[i] + scratch[N + i] + scratch[2 * N + i] + scratch[3 * N + i];
  __syncthreads();
}

// ---------------- transpose+cast body: fp32 [K][N] -> bf16 [N][K], one 32x32 tile ----------------
__device__ __forceinline__ void transcast_body(
    const float* __restrict__ in, int ldin, u16t* __restrict__ out, int ldout,
    int nbi, int kbi, float (*tile)[33]) {
  int tx = threadIdx.x & 31, ty = threadIdx.x >> 5;
  int nb = nbi * 32, kb = kbi * 32;
#pragma unroll
  for (int r = 0; r < 4; r++)
    tile[ty + r * 8][tx] = in[(i64)(kb + ty + r * 8) * ldin + nb + tx];
  __syncthreads();
#pragma unroll
  for (int r = 0; r < 4; r++)
    out[(i64)(nb + ty + r * 8) * ldout + kb + tx] = f2bf(tile[tx][ty + r * 8]);
}

// ---------------- prep (step 1): WqkvT(3072) + xbf(2048) + beta(2048) ----------------
__global__ __launch_bounds__(256) void prep_kernel(
    const float* __restrict__ Wq, const float* __restrict__ Wk, const float* __restrict__ Wv,
    const float* __restrict__ x, const float* __restrict__ Wb,
    u16t* __restrict__ WqkvT, u16t* __restrict__ xbf, float* __restrict__ betab) {
  __shared__ float tile[32][33];
  int blk = blockIdx.x, t = threadIdx.x;
  if (blk < 3072) {
    int m = blk >> 10, bi = blk & 1023;
    const float* in = m == 0 ? Wq : m == 1 ? Wk : Wv;
    transcast_body(in, 1024, WqkvT + (i64)m * 1024 * 1024, 1024, bi & 31, bi >> 5, tile);
  } else if (blk < 5120) {
    i64 e = ((i64)(blk - 3072) * 256 + t) * 4;
    float4 v = *(const float4*)(x + e);
    uint2 o;
    o.x = pk2(f2bf(v.x), f2bf(v.y));
    o.y = pk2(f2bf(v.z), f2bf(v.w));
    *(uint2*)(xbf + e) = o;
  } else {
    int row = blk - 5120;
    float a[4] = {0, 0, 0, 0};
    for (int c = t; c < 1024; c += 256) {
      float xv = x[(i64)row * 1024 + c];
      float4 wv = *(const float4*)(Wb + c * 4);
      a[0] += xv * wv.x; a[1] += xv * wv.y; a[2] += xv * wv.z; a[3] += xv * wv.w;
    }
    block_reduce_sum<4>(a, (float*)tile);
    if (t == 0) {
#pragma unroll
      for (int g = 0; g < 4; g++) betab[row * 4 + g] = sigmoidf_(a[g]);
    }
  }
}

// ---------------- bf16 MFMA GEMM body: A[M][K], B[N][K] -> C[M][N] fp32 ----------------
// Staging via global_load_lds width=16 (Common-mistake #1 fix): linear
// [128][32] u16t LDS tiles, 1KB per wave-instruction. Chunk c (16 rows):
// lane l covers row c*16+(l>>2), u16 cols (l&3)*8..+8 -> LDS offset l*16B
// == row-major (r*32 + col). Wave w stages chunks {2w, 2w+1} of A and B.
__device__ __forceinline__ void gemm_bt_body(
    const u16t* __restrict__ A, const u16t* __restrict__ B,
    float* __restrict__ C, int K, int ldc, int n0, int m0,
    u16t* As, u16t* Bs) {
  int t = threadIdx.x;
  int w = t >> 6, lane = t & 63;
  int l15 = lane & 15, quad = lane >> 4;
  int wm = (w & 1) * 64, wn = (w >> 1) * 64;
  f32x4 acc[4][4] = {};
  int c0 = 2 * w, c1 = 2 * w + 1;
  int srow0 = c0 * 16 + (lane >> 2);
  int srow1 = c1 * 16 + (lane >> 2);
  int scol = (lane & 3) * 8;
  const u16t* Ag0 = A + (i64)(m0 + srow0) * K + scol;
  const u16t* Ag1 = A + (i64)(m0 + srow1) * K + scol;
  const u16t* Bg0 = B + (i64)(n0 + srow0) * K + scol;
  const u16t* Bg1 = B + (i64)(n0 + srow1) * K + scol;
  u16t* As0 = As + c0 * 512;  // wave-uniform LDS bases
  u16t* As1 = As + c1 * 512;
  u16t* Bs0 = Bs + c0 * 512;
  u16t* Bs1 = Bs + c1 * 512;
  for (int k0 = 0; k0 < K; k0 += 32) {
    async_load16(Ag0 + k0, As0);
    async_load16(Ag1 + k0, As1);
    async_load16(Bg0 + k0, Bs0);
    async_load16(Bg1 + k0, Bs1);
    __syncthreads();   // drains vmcnt(0) -> LDS writes visible
    short8 a[4], b[4];
#pragma unroll
    for (int mt = 0; mt < 4; mt++)
      a[mt] = *(const short8*)&As[(wm + mt * 16 + l15) * 32 + quad * 8];
#pragma unroll
    for (int nt = 0; nt < 4; nt++)
      b[nt] = *(const short8*)&Bs[(wn + nt * 16 + l15) * 32 + quad * 8];
#pragma unroll
    for (int mt = 0; mt < 4; mt++)
#pragma unroll
      for (int nt = 0; nt < 4; nt++)
        acc[mt][nt] = MFMA_BF16(a[mt], b[nt], acc[mt][nt]);
    __syncthreads();
  }
#pragma unroll
  for (int mt = 0; mt < 4; mt++) {
    int r0 = m0 + wm + mt * 16 + quad * 4;
#pragma unroll
    for (int nt = 0; nt < 4; nt++) {
      int cc = n0 + wn + nt * 16 + l15;
#pragma unroll
      for (int rg = 0; rg < 4; rg++)
        C[(i64)(r0 + rg) * ldc + cc] = acc[mt][nt][rg];
    }
  }
}

__global__ __launch_bounds__(256) void gemm_bt_kernel(
    const u16t* __restrict__ A, const u16t* __restrict__ B,
    float* __restrict__ C, int K, int ldc) {
  __shared__ u16t As[128 * 32];
  __shared__ u16t Bs[128 * 32];
  gemm_bt_body(A, B, C, K, ldc, blockIdx.x * 128, blockIdx.y * 128, As, Bs);
}

// ---------------- fused causal depthwise conv (K=4) + silu, VECTORIZED x4 ----------------
__global__ __launch_bounds__(256) void conv_silu3_kernel(
    const float* __restrict__ pre, const float* __restrict__ qw,
    const float* __restrict__ kw, const float* __restrict__ vw,
    float* __restrict__ qo, float* __restrict__ ko, float* __restrict__ vo,
    u16t* __restrict__ brcat) {
  int seg = blockIdx.x >> 11;          // 3 segs x 2048 rows
  int row = blockIdx.x & 2047;         // b*1024 + l
  int l = row & 1023;
  int c = threadIdx.x * 4;
  const float* w = seg == 0 ? qw : seg == 1 ? kw : vw;
  float* out = seg == 0 ? qo : seg == 1 ? ko : vo;
  float4 w0 = *(const float4*)(w + (i64)(c + 0) * 4);
  float4 w1 = *(const float4*)(w + (i64)(c + 1) * 4);
  float4 w2 = *(const float4*)(w + (i64)(c + 2) * 4);
  float4 w3 = *(const float4*)(w + (i64)(c + 3) * 4);
  const float* base = pre + (i64)row * 3072 + (seg << 10) + c;
  float4 x0 = *(const float4*)(base);
  float4 acc;
  acc.x = w0.w * x0.x; acc.y = w1.w * x0.y; acc.z = w2.w * x0.z; acc.w = w3.w * x0.w;
  if (l >= 1) {
    float4 xm = *(const float4*)(base - 3072);
    acc.x += w0.z * xm.x; acc.y += w1.z * xm.y; acc.z += w2.z * xm.z; acc.w += w3.z * xm.w;
  }
  if (l >= 2) {
    float4 xm = *(const float4*)(base - 2 * 3072);
    acc.x += w0.y * xm.x; acc.y += w1.y * xm.y; acc.z += w2.y * xm.z; acc.w += w3.y * xm.w;
  }
  if (l >= 3) {
    float4 xm = *(const float4*)(base - 3 * 3072);
    acc.x += w0.x * xm.x; acc.y += w1.x * xm.y; acc.z += w2.x * xm.z; acc.w += w3.x * xm.w;
  }
  float4 r;
  r.x = acc.x * sigmoidf_(acc.x);
  r.y = acc.y * sigmoidf_(acc.y);
  r.z = acc.z * sigmoidf_(acc.z);
  r.w = acc.w * sigmoidf_(acc.w);
  *(float4*)(out + (i64)row * 1024 + c) = r;
  if (seg == 2) {
    uint2 o;
    o.x = cvt_pk_bf16(r.x, r.y);
    o.y = cvt_pk_bf16(r.z, r.w);
    *(uint2*)(brcat + ((i64)row * 4 + (c >> 8)) * 1024 + 768 + (c & 255)) = o;
  }
}

// ---------------- preprocess: WAVE-PER-ROW, float4 (G13) ----------------
__global__ __launch_bounds__(256) void preprocess_kernel(
    const float* __restrict__ q, const float* __restrict__ k, const float* __restrict__ v,
    const float* __restrict__ beta, float* __restrict__ qn, float* __restrict__ kn,
    float* __restrict__ vb, float* __restrict__ kb, u16t* __restrict__ qnbf) {
  int t = threadIdx.x, lane = t & 63, wv = t >> 6;
  int row = blockIdx.x * 4 + wv;       // (b*1024+l)*4+h
  i64 base = (i64)row * 256 + lane * 4;
  float4 q4 = *(const float4*)(q + base);
  float4 k4 = *(const float4*)(k + base);
  float4 v4 = *(const float4*)(v + base);
  float s2[2];
  s2[0] = q4.x * q4.x + q4.y * q4.y + q4.z * q4.z + q4.w * q4.w;
  s2[1] = k4.x * k4.x + k4.y * k4.y + k4.z * k4.z + k4.w * k4.w;
#pragma unroll
  for (int off = 1; off < 64; off <<= 1) {
    s2[0] += __shfl_xor(s2[0], off);
    s2[1] += __shfl_xor(s2[1], off);
  }
  float qi = rsqrtf(s2[0] + 1e-6f), ki = rsqrtf(s2[1] + 1e-6f);
  float bet = beta[row];
  float4 qn4, kn4, vb4, kb4;
  qn4.x = q4.x * qi; qn4.y = q4.y * qi; qn4.z = q4.z * qi; qn4.w = q4.w * qi;
  kn4.x = k4.x * ki; kn4.y = k4.y * ki; kn4.z = k4.z * ki; kn4.w = k4.w * ki;
  vb4.x = v4.x * bet; vb4.y = v4.y * bet; vb4.z = v4.z * bet; vb4.w = v4.w * bet;
  kb4.x = kn4.x * bet; kb4.y = kn4.y * bet; kb4.z = kn4.z * bet; kb4.w = kn4.w * bet;
  *(float4*)(qn + base) = qn4;
  *(float4*)(kn + base) = kn4;
  *(float4*)(vb + base) = vb4;
  *(float4*)(kb + base) = kb4;
  int b = row >> 12, l = (row >> 2) & 1023, h = row & 3;
  uint2 o;
  o.x = cvt_pk_bf16(qn4.x, qn4.y);
  o.y = cvt_pk_bf16(qn4.z, qn4.w);
  *(uint2*)(qnbf + ((i64)(b * 4 + h) * 1024 + l) * 256 + lane * 4) = o;
}

// ---------------- phaseA2: phaseA(256) + W1/Wo transposes(2048) + wsum(24) ----
__global__ __launch_bounds__(256) void phaseA2_kernel(
    const float* __restrict__ qn, const float* __restrict__ kn,
    const float* __restrict__ vb, const float* __restrict__ kb,
    float* __restrict__ u_g, u16t* __restrict__ w_bf, u16t* __restrict__ attn_bf,
    u16t* __restrict__ knT,
    const float* __restrict__ gW1, const float* __restrict__ Wo,
    u16t* __restrict__ W1hT, u16t* __restrict__ W1bT, u16t* __restrict__ WoT,
    float* __restrict__ wsum) {
  __shared__ __attribute__((aligned(16))) char smem[37376];
  int blk = blockIdx.x, t = threadIdx.x;
  if (blk < 256) {
    float (*KN)[260] = (float(*)[260])smem;          // 33280 B
    float (*Ms)[32] = (float(*)[32])(smem + 33280);  // 4096 B
    int i = blk & 31, bh = blk >> 5;
    int rbase = ((bh >> 2) * LL + i * 32) * NH + (bh & 3);
    i64 bhn = blk;
#pragma unroll
    for (int ii = 0; ii < 8; ii++) {
      int fid = t + ii * 256;
      int c = fid >> 6, dq = (fid & 63) << 2;
      *(float4*)&KN[c][dq] = *(const float4*)(kn + (i64)(rbase + c * NH) * 256 + dq);
    }
    __syncthreads();
    int c = t >> 3, e0 = (t & 7) * 4;
    const float* kbp = kb + (i64)(rbase + c * NH) * 256;
    const float* qp = qn + (i64)(rbase + c * NH) * 256;
    float am[4] = {0, 0, 0, 0}, aa[4] = {0, 0, 0, 0};
    for (int d = 0; d < 256; d += 4) {
      float4 kv = *(const float4*)(kbp + d);
      float4 qv = *(const float4*)(qp + d);
#pragma unroll
      for (int z = 0; z < 4; z++) {
        float4 nv = *(const float4*)&KN[e0 + z][d];
        am[z] += kv.x * nv.x + kv.y * nv.y + kv.z * nv.z + kv.w * nv.w;
        aa[z] += qv.x * nv.x + qv.y * nv.y + qv.z * nv.z + qv.w * nv.w;
      }
    }
    {
      uint2 o;
      u16t a0 = (e0 + 0 <= c) ? f2bf(aa[0]) : 0;
      u16t a1 = (e0 + 1 <= c) ? f2bf(aa[1]) : 0;
      u16t a2 = (e0 + 2 <= c) ? f2bf(aa[2]) : 0;
      u16t a3 = (e0 + 3 <= c) ? f2bf(aa[3]) : 0;
      o.x = pk2(a0, a1); o.y = pk2(a2, a3);
      *(uint2*)(attn_bf + bhn * 1024 + c * 32 + e0) = o;
    }
#pragma unroll
    for (int z = 0; z < 4; z++) {
      int e = e0 + z;
      Ms[c][e] = (e < c) ? am[z] : 0.0f;
    }
    __syncthreads();
    float uc[32], wc[32];
#pragma unroll
    for (int cc = 0; cc < 32; cc++) {
      float uval = vb[(i64)(rbase + cc * NH) * 256 + t];
      float wval = kb[(i64)(rbase + cc * NH) * 256 + t];
#pragma unroll
      for (int c2 = 0; c2 < cc; c2++) {
        float m = Ms[cc][c2];
        uval -= m * uc[c2];
        wval -= m * wc[c2];
      }
      uc[cc] = uval; wc[cc] = wval;
      u_g[(bhn * 32 + cc) * 256 + t] = uval;
      w_bf[(bhn * 32 + cc) * 256 + t] = f2bf(-wval);
    }
    int d = t;
    u16t o[32];
#pragma unroll
    for (int cc = 0; cc < 32; cc++) o[cc] = f2bf(KN[cc][d]);
#pragma unroll
    for (int z = 0; z < 4; z++) {
      uint4 vv;
      vv.x = pk2(o[z * 8 + 0], o[z * 8 + 1]);
      vv.y = pk2(o[z * 8 + 2], o[z * 8 + 3]);
      vv.z = pk2(o[z * 8 + 4], o[z * 8 + 5]);
      vv.w = pk2(o[z * 8 + 6], o[z * 8 + 7]);
      *(uint4*)(knT + (bhn * 256 + d) * 32 + z * 8) = vv;
    }
  } else if (blk < 2304) {
    float (*tile)[33] = (float(*)[33])smem;
    int pb = blk - 256;
    if (pb < 1024) {
      int which = pb >> 9, bi = pb & 511;
      const float* in = gW1 + (which ? (i64)4096 * 512 : 0);
      transcast_body(in, 512, which ? W1bT : W1hT, 1024, bi & 15, bi >> 4, tile);
    } else {
      int bi = pb - 1024;
      transcast_body(Wo, 1024, WoT, 1024, bi & 31, bi >> 5, tile);
    }
  } else {
    int bi = blk - 2304;         // 24 blocks: 12 stats x 2 col-halves
    int s12 = bi >> 1, col = (bi & 1) * 256 + t;
    const float* p = gW1 + (i64)(1024 + s12 * 256) * 512 + col;
    float acc = 0.0f;
    for (int r = 0; r < 256; r++) acc += p[(i64)r * 512];
    wsum[s12 * 512 + col] = acc;
  }
}

// ---------------- delta scan body (verbatim passing version) ----------------
#define SROW 264
struct ScanBuf {
  short8 m8[8];
  f32x4 uc4;
  short8 af;
  short8 kf[4];
};

__device__ void delta_scan_body(
    int blk,
    const u16t* __restrict__ wbf, const u16t* __restrict__ knT,
    const float* __restrict__ u_g, const u16t* __restrict__ qnbf,
    const u16t* __restrict__ attnbf,
    float* __restrict__ dlt, u16t* __restrict__ brcat,
    u16t* Sbf, u16t* Ubf) {
  int t = threadIdx.x, w = t >> 6, lane = t & 63;
  int l15 = lane & 15, quad = lane >> 4;
  int bh = blk & 7, jb = blk >> 3, j0 = jb * 16;
  int b_ = bh >> 2, h_ = bh & 3;
  bool isU = (w < 2);
  int wc = isU ? w : (w - 2);
  for (int idx = t; idx < 16 * SROW; idx += 256) Sbf[idx] = 0;
  f32x4 accS[4] = {};
  __syncthreads();
  __builtin_amdgcn_s_setprio(1);

  auto load_chunk = [&](int i, ScanBuf& B) {
    i64 bhn = (i64)bh * 32 + i;
    const u16t* mbase = isU
        ? wbf + (bhn * 32 + wc * 16 + l15) * 256 + quad * 8
        : qnbf + ((i64)bh * 1024 + i * 32 + wc * 16 + l15) * 256 + quad * 8;
#pragma unroll
    for (int kd = 0; kd < 8; kd++) B.m8[kd] = *(const short8*)(mbase + kd * 32);
    if (isU) {
      int cm = wc * 16 + quad * 4;
#pragma unroll
      for (int r = 0; r < 4; r++)
        B.uc4[r] = u_g[(bhn * 32 + cm + r) * 256 + j0 + l15];
    } else {
      B.af = *(const short8*)(attnbf + bhn * 1024 + (wc * 16 + l15) * 32 + quad * 8);
    }
#pragma unroll
    for (int dt = 0; dt < 4; dt++)
      B.kf[dt] = *(const short8*)(knT + (bhn * 256 + w * 64 + dt * 16 + l15) * 32 + quad * 8);
  };

  auto process = [&](int i, ScanBuf& B) {
    f32x4 zero = {};
    f32x4 ca = isU ? B.uc4 : zero;
    f32x4 cb = zero;
#pragma unroll
    for (int kd = 0; kd < 4; kd++) {
      short8 sfa = *(const short8*)&Sbf[l15 * SROW + kd * 32 + quad * 8];
      short8 sfb = *(const short8*)&Sbf[l15 * SROW + (kd + 4) * 32 + quad * 8];
      ca = MFMA_BF16(B.m8[kd], sfa, ca);
      cb = MFMA_BF16(B.m8[kd + 4], sfb, cb);
    }
    f32x4 cacc;
#pragma unroll
    for (int r = 0; r < 4; r++) cacc[r] = ca[r] + cb[r];
    if (isU) {
      int cm = wc * 16 + quad * 4;
      uint2 o;
      o.x = cvt_pk_bf16(cacc[0], cacc[1]);
      o.y = cvt_pk_bf16(cacc[2], cacc[3]);
      *(uint2*)&Ubf[l15 * 40 + cm] = o;
    }
    barrier_lds_only();
    short8 bu = *(const short8*)&Ubf[l15 * 40 + quad * 8];
    if (!isU) {
      cacc = MFMA_BF16(B.af, bu, cacc);
#pragma unroll
      for (int rg = 0; rg < 4; rg++) {
        int l = i * 32 + wc * 16 + quad * 4 + rg;
        i64 row = ((i64)b_ * 1024 + l) * 4 + h_;
        dlt[row * 256 + j0 + l15] = cacc[rg];
        brcat[row * 1024 + 512 + j0 + l15] = f2bf(cacc[rg]);
      }
    }
#pragma unroll
    for (int dt = 0; dt < 4; dt++) accS[dt] = MFMA_BF16(B.kf[dt], bu, accS[dt]);
#pragma unroll
    for (int dt = 0; dt < 4; dt++) {
      uint2 o;
      o.x = cvt_pk_bf16(accS[dt][0], accS[dt][1]);
      o.y = cvt_pk_bf16(accS[dt][2], accS[dt][3]);
      *(uint2*)&Sbf[l15 * SROW + w * 64 + dt * 16 + quad * 4] = o;
    }
    barrier_lds_only();
  };

  ScanBuf b0, b1;
  load_chunk(0, b0);
#pragma unroll 1
  for (int ii = 0; ii < 16; ii++) {
    int i = ii * 2;
    load_chunk(i + 1, b1);
    process(i, b0);
    if (ii < 15) load_chunk(i + 2, b0);
    process(i + 1, b1);
  }
  __builtin_amdgcn_s_setprio(0);
}

// ---------------- FIR body ----------------
__device__ void fir2_body(
    int blk, const float* __restrict__ v,
    const float* __restrict__ f_s, const float* __restrict__ f_l,
    float* __restrict__ fs, float* __restrict__ fl, u16t* __restrict__ brcat) {
  int t = threadIdx.x;
  int b = blk >> 8, h = (blk >> 6) & 3, lc = blk & 63;
  int l0 = lc * 16;
  float flw[31], fsw[3];
  const float* flp = f_l + ((i64)h * 256 + t) * 31;
#pragma unroll
  for (int j = 0; j < 31; j++) flw[j] = flp[j];
  const float* fsp = f_s + ((i64)h * 256 + t) * 3;
#pragma unroll
  for (int j = 0; j < 3; j++) fsw[j] = fsp[j];
  float win[46];
#pragma unroll
  for (int r = 0; r < 46; r++) {
    int l = l0 - 30 + r;
    win[r] = (l >= 0) ? v[(((i64)b * 1024 + l) * 4 + h) * 256 + t] : 0.0f;
  }
#pragma unroll
  for (int i = 0; i < 16; i++) {
    float al = 0.0f;
#pragma unroll
    for (int j = 0; j < 31; j++) al += flw[j] * win[i + j];
    float as = fsw[0] * win[i + 28] + fsw[1] * win[i + 29] + fsw[2] * win[i + 30];
    i64 row = ((i64)b * 1024 + (l0 + i)) * 4 + h;
    fs[row * 256 + t] = as;
    fl[row * 256 + t] = al;
    brcat[row * 1024 + t] = f2bf(as);
    brcat[row * 1024 + 256 + t] = f2bf(al);
  }
}

// ---------------- mega5: scan(128) + fir(512) + hbase gemm(64) ----------------
__global__ __launch_bounds__(256) void mega5_kernel(
    const u16t* __restrict__ wbf, const u16t* __restrict__ knT,
    const float* __restrict__ u_g, const u16t* __restrict__ qnbf,
    const u16t* __restrict__ attnbf, float* __restrict__ dlt, u16t* __restrict__ brcat,
    const float* __restrict__ vbuf, const float* __restrict__ firs,
    const float* __restrict__ firl, float* __restrict__ fs, float* __restrict__ fl,
    const u16t* __restrict__ xbf, const u16t* __restrict__ W1hT,
    float* __restrict__ hbase) {
  __shared__ __attribute__((aligned(16))) char smem[16384];
  int blk = blockIdx.x;
  if (blk < 128) {
    u16t* Sbf = (u16t*)smem;
    u16t* Ubf = Sbf + 16 * SROW;
    delta_scan_body(blk, wbf, knT, u_g, qnbf, attnbf, dlt, brcat, Sbf, Ubf);
  } else if (blk < 640) {
    fir2_body(blk - 128, vbuf, firs, firl, fs, fl, brcat);
  } else {
    int bi = blk - 640;
    u16t* As = (u16t*)smem;
    u16t* Bs = As + 128 * 32;
    gemm_bt_body(xbf, W1hT, hbase, 1024, 512, (bi & 3) * 128, (bi >> 2) * 128, As, Bs);
  }
}

// ---------------- gate MLP tail + mix + RMS norm: WAVE-PER-ROW ----------------
__global__ __launch_bounds__(256) void gatemix_kernel(
    const float* __restrict__ hbase, const float* __restrict__ brW,
    const float* __restrict__ wsum,
    const float* __restrict__ gb1, const float* __restrict__ gW2,
    const float* __restrict__ gb2, const float* __restrict__ temp,
    const float* __restrict__ epsf,
    const float* __restrict__ fs, const float* __restrict__ fl,
    const float* __restrict__ dlt, const float* __restrict__ v,
    const float* __restrict__ onw, u16t* __restrict__ out) {
  int t = threadIdx.x, lane = t & 63, wv = t >> 6;
  int row = blockIdx.x * 4 + wv;      // (b*1024+l)*4+h
  int bl = row >> 2, h = row & 3;
  i64 base = (i64)row * 256 + lane * 4;
  float4 vfs = *(const float4*)(fs + base);
  float4 vfl = *(const float4*)(fl + base);
  float4 vdl = *(const float4*)(dlt + base);
  float4 vvv = *(const float4*)(v + base);
  float r8[8];
  r8[0] = vfs.x + vfs.y + vfs.z + vfs.w;
  r8[1] = vfs.x * vfs.x + vfs.y * vfs.y + vfs.z * vfs.z + vfs.w * vfs.w;
  r8[2] = vfl.x + vfl.y + vfl.z + vfl.w;
  r8[3] = vfl.x * vfl.x + vfl.y * vfl.y + vfl.z * vfl.z + vfl.w * vfl.w;
  r8[4] = vdl.x + vdl.y + vdl.z + vdl.w;
  r8[5] = vdl.x * vdl.x + vdl.y * vdl.y + vdl.z * vdl.z + vdl.w * vdl.w;
  r8[6] = vvv.x + vvv.y + vvv.z + vvv.w;
  r8[7] = vvv.x * vvv.x + vvv.y * vvv.y + vvv.z * vvv.z + vvv.w * vvv.w;
#pragma unroll
  for (int off = 1; off < 64; off <<= 1) {
#pragma unroll
    for (int i = 0; i < 8; i++) r8[i] += __shfl_xor(r8[i], off);
  }
  float m4[4];
  m4[0] = fmaxf(fmaxf(vfs.x, vfs.y), fmaxf(vfs.z, vfs.w));
  m4[1] = fmaxf(fmaxf(vfl.x, vfl.y), fmaxf(vfl.z, vfl.w));
  m4[2] = fmaxf(fmaxf(vdl.x, vdl.y), fmaxf(vdl.z, vdl.w));
  m4[3] = fmaxf(fmaxf(vvv.x, vvv.y), fmaxf(vvv.z, vvv.w));
#pragma unroll
  for (int off = 1; off < 64; off <<= 1) {
#pragma unroll
    for (int i = 0; i < 4; i++) m4[i] = fmaxf(m4[i], __shfl_xor(m4[i], off));
  }
  float st[12];
#pragma unroll
  for (int p = 0; p < 4; p++) {
    st[p * 3 + 0] = r8[p * 2] * (1.0f / 256.0f);
    st[p * 3 + 1] = sqrtf(fmaxf(r8[p * 2 + 1] * (1.0f / 256.0f), 1e-8f));
    st[p * 3 + 2] = m4[p];
  }
  float lg[4] = {0, 0, 0, 0};
#pragma unroll
  for (int jj = 0; jj < 8; jj++) {
    int o = jj * 64 + lane;
    float hm = hbase[(i64)bl * 512 + o] + brW[(i64)row * 512 + o] + gb1[o];
#pragma unroll
    for (int s = 0; s < 12; s++) hm += st[s] * wsum[s * 512 + o];
    float ge = 0.5f * hm * (1.0f + erff(hm * 0.70710678118654752f));
    float4 w2 = *(const float4*)(gW2 + o * 4);
    lg[0] += ge * w2.x; lg[1] += ge * w2.y; lg[2] += ge * w2.z; lg[3] += ge * w2.w;
  }
#pragma unroll
  for (int off = 1; off < 64; off <<= 1) {
#pragma unroll
    for (int i = 0; i < 4; i++) lg[i] += __shfl_xor(lg[i], off);
  }
  float tt = fminf(fmaxf(temp[h], 0.2f), 10.0f);
  float l0 = (lg[0] + gb2[0]) / tt;
  float l1 = (lg[1] + gb2[1]) / tt;
  float l2 = (lg[2] + gb2[2]) / tt;
  float l3 = (lg[3] + gb2[3]) / tt;
  float m = fmaxf(fmaxf(l0, l1), fmaxf(l2, l3));
  float e0 = expf(l0 - m), e1 = expf(l1 - m), e2 = expf(l2 - m), e3 = expf(l3 - m);
  float ssum = e0 + e1 + e2 + e3;
  float w0 = e0 / ssum, w1 = e1 / ssum, w2 = e2 / ssum, w3 = e3 / ssum;
  w0 = fmaxf(w0, fminf(fmaxf(epsf[h * 4 + 0], 1e-7f), 0.1f));
  w1 = fmaxf(w1, fminf(fmaxf(epsf[h * 4 + 1], 1e-7f), 0.1f));
  w2 = fmaxf(w2, fminf(fmaxf(epsf[h * 4 + 2], 1e-7f), 0.1f));
  w3 = fmaxf(w3, fminf(fmaxf(epsf[h * 4 + 3], 1e-7f), 0.1f));
  float s2 = w0 + w1 + w2 + w3;
  float g0 = w0 / s2, g1 = w1 / s2, g2 = w2 / s2, g3 = w3 / s2;
  float4 o4;
  o4.x = g0 * vfs.x + g1 * vfl.x + g2 * vdl.x + g3 * vvv.x;
  o4.y = g0 * vfs.y + g1 * vfl.y + g2 * vdl.y + g3 * vvv.y;
  o4.z = g0 * vfs.z + g1 * vfl.z + g2 * vdl.z + g3 * vvv.z;
  o4.w = g0 * vfs.w + g1 * vfl.w + g2 * vdl.w + g3 * vvv.w;
  float ss = o4.x * o4.x + o4.y * o4.y + o4.z * o4.z + o4.w * o4.w;
#pragma unroll
  for (int off = 1; off < 64; off <<= 1) ss += __shfl_xor(ss, off);
  float scale = rsqrtf(ss * (1.0f / 256.0f) + 1e-5f);
  float4 ow4 = *(const float4*)(onw + lane * 4);
  uint2 ow;
  ow.x = cvt_pk_bf16(o4.x * scale * ow4.x, o4.y * scale * ow4.y);
  ow.y = cvt_pk_bf16(o4.z * scale * ow4.z, o4.w * scale * ow4.w);
  *(uint2*)(out + (i64)bl * 1024 + h * 256 + lane * 4) = ow;
}

extern "C" void kernel_launch(void* const* d_in, const int* in_sizes, int n_in,
                              void* d_out, int out_size, void* d_ws, size_t ws_size,
                              hipStream_t stream) {
  (void)in_sizes; (void)n_in; (void)out_size; (void)ws_size;
  const float* x    = (const float*)d_in[0];
  const float* Wq   = (const float*)d_in[1];
  const float* Wk   = (const float*)d_in[2];
  const float* Wv   = (const float*)d_in[3];
  const float* Wb   = (const float*)d_in[4];
  const float* qcw  = (const float*)d_in[5];
  const float* kcw  = (const float*)d_in[6];
  const float* vcw  = (const float*)d_in[7];
  const float* gW1  = (const float*)d_in[8];
  const float* gb1  = (const float*)d_in[9];
  const float* gW2  = (const float*)d_in[10];
  const float* gb2  = (const float*)d_in[11];
  const float* temp = (const float*)d_in[12];
  const float* epsf = (const float*)d_in[13];
  const float* onw  = (const float*)d_in[14];
  const float* Wo   = (const float*)d_in[15];
  const float* firs = (const float*)d_in[16];
  const float* firl = (const float*)d_in[17];
  float* out = (float*)d_out;

  float* ws = (float*)d_ws;
  // ---- workspace map (float offsets) ----
  float* qkv_pre  = ws + 0;                       // 2048*3072 fp32 (dead after conv)
  float* branchW  = ws + 0;                       // 8192*512 fp32 (step 7+)
  float* hbase    = ws + 4194304;                 // 2048*512 fp32 (step 6+)
  u16t*  W1hT     = (u16t*)(ws + 5242880);        // 512x1024 bf16 (step 5+)
  u16t*  W1bT     = (u16t*)(ws + 5505024);        // 512x1024 bf16
  u16t*  WoT      = (u16t*)(ws + 5767168);        // 1024x1024 bf16
  u16t*  brcat    = (u16t*)(ws + 6291456);        // 8192*1024 bf16
  float* qbuf     = ws + 10485760; float* qn = qbuf;
  float* kbuf     = ws + 12582912; float* kn = kbuf;
  float* vbuf     = ws + 14680064;
  float* vb       = ws + 16777216;                // dead after phaseA2
  u16t*  omix_bf  = (u16t*)(ws + 16777216);       // gatemix+ (2048*1024 bf16)
  float* kb       = ws + 18874368;                // dead after phaseA2
  float* dlt      = ws + 18874368;                // scan output
  float* u_g      = ws + 20971520;
  u16t*  w_bf     = (u16t*)(ws + 23068672);
  u16t*  qn_bf    = (u16t*)(ws + 24117248);
  u16t*  knT      = (u16t*)(ws + 25165824);
  u16t*  attn_bf  = (u16t*)(ws + 26214400);
  float* fs       = ws + 26345472;
  float* fl       = ws + 28442624;
  u16t*  xbf      = (u16t*)(ws + 30539776);
  u16t*  WqkvT    = (u16t*)(ws + 31588352);
  float* betab    = ws + 33161216;                // 8192 fp32
  float* wsum     = ws + 33267712;

  // 1) prep: QKV weight transpose + x cast + beta
  prep_kernel<<<7168, 256, 0, stream>>>(Wq, Wk, Wv, x, Wb, WqkvT, xbf, betab);
  // 2) QKV GEMM (global_load_lds staging)
  gemm_bt_kernel<<<dim3(24, 16), 256, 0, stream>>>(xbf, WqkvT, qkv_pre, 1024, 3072);
  // 3) conv+silu vectorized x4 (v also -> brcat col 768); kills qkv_pre
  conv_silu3_kernel<<<6144, 256, 0, stream>>>(qkv_pre, qcw, kcw, vcw, qbuf, kbuf, vbuf, brcat);
  // 4) preprocess (wave-per-row, float4)
  preprocess_kernel<<<2048, 256, 0, stream>>>(qbuf, kbuf, vbuf, betab, qn, kn, vb, kb, qn_bf);
  // 5) phaseA2: UT-transform + W1/Wo transposes (into dead qkv_pre) + wsum
  phaseA2_kernel<<<2328, 256, 0, stream>>>(qn, kn, vb, kb, u_g, w_bf, attn_bf, knT,
                                           gW1, Wo, W1hT, W1bT, WoT, wsum);
  // 6) mega5: scan + FIR + hbase GEMM
  mega5_kernel<<<704, 256, 0, stream>>>(w_bf, knT, u_g, qn_bf, attn_bf, dlt, brcat,
                                        vbuf, firs, firl, fs, fl,
                                        xbf, W1hT, hbase);
  // 7) branchW GEMM
  gemm_bt_kernel<<<dim3(4, 64), 256, 0, stream>>>(brcat, W1bT, branchW, 1024, 512);
  // 8) gate tail + mix + RMS (wave-per-row, no barriers)
  gatemix_kernel<<<2048, 256, 0, stream>>>(hbase, branchW, wsum, gb1, gW2, gb2,
                                           temp, epsf, fs, fl, dlt, vbuf, onw, omix_bf);
  // 9) final projection
  gemm_bt_kernel<<<dim3(8, 16), 256, 0, stream>>>(omix_bf, WoT, out, 1024, 1024);
}

// Round 11
// 316.607 us; speedup vs baseline: 1.0826x; 1.0361x over previous
//
#include <hip/hip_runtime.h>
#include <math.h>

// Problem constants
#define BB 2
#define LL 1024
#define HIDD 1024
#define NH 4
#define DD 256
#define NCH 32
#define ROWS 2048
#define HROWS 8192

typedef long long i64;
typedef unsigned short u16t;
typedef unsigned int u32t;
typedef __attribute__((ext_vector_type(8))) short short8;
typedef __attribute__((ext_vector_type(4))) float f32x4;
#define MFMA_BF16(a, b, c) __builtin_amdgcn_mfma_f32_16x16x32_bf16(a, b, c, 0, 0, 0)

__device__ __forceinline__ float sigmoidf_(float x) { return 1.0f / (1.0f + expf(-x)); }

__device__ __forceinline__ u16t f2bf(float f) {
  u32t u = __float_as_uint(f);
  u = u + 0x7FFFu + ((u >> 16) & 1u);
  return (u16t)(u >> 16);
}
__device__ __forceinline__ u32t pk2(u16t a, u16t b) { return (u32t)a | ((u32t)b << 16); }

// HW packed f32->bf16 RNE convert (gfx950): 1 instr vs 6-op bit-trick pair.
__device__ __forceinline__ u32t cvt_pk_bf16(float lo, float hi) {
  u32t r;
  asm("v_cvt_pk_bf16_f32 %0, %1, %2" : "=v"(r) : "v"(lo), "v"(hi));
  return r;
}

// async global->LDS, 16B per lane. HW writes lane l's 16B at lds_base + l*16
// (wave-uniform LDS base, per-lane global src). Counted in vmcnt; the
// vmcnt(0) inside __syncthreads drains it.
__device__ __forceinline__ void async_load16(const u16t* g, u16t* l) {
  __builtin_amdgcn_global_load_lds(
      (const __attribute__((address_space(1))) u32t*)g,
      (__attribute__((address_space(3))) u32t*)l, 16, 0, 0);
}

// counted-wait barrier: drain only LDS ops, keep global loads in flight.
__device__ __forceinline__ void barrier_lds_only() {
  asm volatile("s_waitcnt lgkmcnt(0)" ::: "memory");
  __builtin_amdgcn_s_barrier();
  asm volatile("" ::: "memory");
}

// ---------------- block reduction helper (blockDim == 256) ----------------
template<int N>
__device__ __forceinline__ void block_reduce_sum(float* v, float* scratch) {
  int lane = threadIdx.x & 63, wid = threadIdx.x >> 6;
#pragma unroll
  for (int i = 0; i < N; i++) {
    float x = v[i];
#pragma unroll
    for (int off = 1; off < 64; off <<= 1) x += __shfl_xor(x, off);
    if (lane == 0) scratch[wid * N + i] = x;
  }
  __syncthreads();
#pragma unroll
  for (int i = 0; i < N; i++)
    v[i] = scratch[i] + scratch[N + i] + scratch[2 * N + i] + scratch[3 * N + i];
  __syncthreads();
}

// ---------------- transpose+cast body: fp32 [K][N] -> bf16 [N][K], one 32x32 tile ----------------
__device__ __forceinline__ void transcast_body(
    const float* __restrict__ in, int ldin, u16t* __restrict__ out, int ldout,
    int nbi, int kbi, float (*tile)[33]) {
  int tx = threadIdx.x & 31, ty = threadIdx.x >> 5;
  int nb = nbi * 32, kb = kbi * 32;
#pragma unroll
  for (int r = 0; r < 4; r++)
    tile[ty + r * 8][tx] = in[(i64)(kb + ty + r * 8) * ldin + nb + tx];
  __syncthreads();
#pragma unroll
  for (int r = 0; r < 4; r++)
    out[(i64)(nb + ty + r * 8) * ldout + kb + tx] = f2bf(tile[tx][ty + r * 8]);
}

// ---------------- prep (step 1): WqkvT(3072) + xbf(2048) + beta(2048) ----------------
__global__ __launch_bounds__(256) void prep_kernel(
    const float* __restrict__ Wq, const float* __restrict__ Wk, const float* __restrict__ Wv,
    const float* __restrict__ x, const float* __restrict__ Wb,
    u16t* __restrict__ WqkvT, u16t* __restrict__ xbf, float* __restrict__ betab) {
  __shared__ float tile[32][33];
  int blk = blockIdx.x, t = threadIdx.x;
  if (blk < 3072) {
    int m = blk >> 10, bi = blk & 1023;
    const float* in = m == 0 ? Wq : m == 1 ? Wk : Wv;
    transcast_body(in, 1024, WqkvT + (i64)m * 1024 * 1024, 1024, bi & 31, bi >> 5, tile);
  } else if (blk < 5120) {
    i64 e = ((i64)(blk - 3072) * 256 + t) * 4;
    float4 v = *(const float4*)(x + e);
    uint2 o;
    o.x = pk2(f2bf(v.x), f2bf(v.y));
    o.y = pk2(f2bf(v.z), f2bf(v.w));
    *(uint2*)(xbf + e) = o;
  } else {
    int row = blk - 5120;
    float a[4] = {0, 0, 0, 0};
    for (int c = t; c < 1024; c += 256) {
      float xv = x[(i64)row * 1024 + c];
      float4 wv = *(const float4*)(Wb + c * 4);
      a[0] += xv * wv.x; a[1] += xv * wv.y; a[2] += xv * wv.z; a[3] += xv * wv.w;
    }
    block_reduce_sum<4>(a, (float*)tile);
    if (t == 0) {
#pragma unroll
      for (int g = 0; g < 4; g++) betab[row * 4 + g] = sigmoidf_(a[g]);
    }
  }
}

// ---------------- bf16 MFMA GEMM body: A[M][K], B[N][K] -> C[M][N] fp32 ----------------
// T3 minimum 2-phase: double-buffered [2][128][32] LDS tiles; next tile's
// global_load_lds issued BEFORE current tile's ds_read+MFMA so its latency
// hides under compute; ONE __syncthreads per K-step (vmcnt(0)+lgkmcnt(0)
// drain inside it makes the prefetched tile visible). Buffer overwritten at
// iter t was last read at iter t-1 (lgkm drained at its barrier) — safe.
__device__ __forceinline__ void gemm_bt_body(
    const u16t* __restrict__ A, const u16t* __restrict__ B,
    float* __restrict__ C, int K, int ldc, int n0, int m0,
    u16t* As, u16t* Bs) {
  int t = threadIdx.x;
  int w = t >> 6, lane = t & 63;
  int l15 = lane & 15, quad = lane >> 4;
  int wm = (w & 1) * 64, wn = (w >> 1) * 64;
  f32x4 acc[4][4] = {};
  int c0 = 2 * w, c1 = 2 * w + 1;
  int srow0 = c0 * 16 + (lane >> 2);
  int srow1 = c1 * 16 + (lane >> 2);
  int scol = (lane & 3) * 8;
  const u16t* Ag0 = A + (i64)(m0 + srow0) * K + scol;
  const u16t* Ag1 = A + (i64)(m0 + srow1) * K + scol;
  const u16t* Bg0 = B + (i64)(n0 + srow0) * K + scol;
  const u16t* Bg1 = B + (i64)(n0 + srow1) * K + scol;
  int lb0 = c0 * 512, lb1 = c1 * 512;   // wave-uniform LDS chunk bases
  // prologue: stage tile 0 into buffer 0
  async_load16(Ag0, As + lb0);
  async_load16(Ag1, As + lb1);
  async_load16(Bg0, Bs + lb0);
  async_load16(Bg1, Bs + lb1);
  __syncthreads();
  int nt = K >> 5;
  for (int ti = 0; ti < nt; ++ti) {
    int cur = (ti & 1) << 12;           // buffer offset (4096 u16)
    if (ti + 1 < nt) {
      int nxt = ((ti + 1) & 1) << 12;
      int k = (ti + 1) << 5;
      async_load16(Ag0 + k, As + nxt + lb0);
      async_load16(Ag1 + k, As + nxt + lb1);
      async_load16(Bg0 + k, Bs + nxt + lb0);
      async_load16(Bg1 + k, Bs + nxt + lb1);
    }
    short8 a[4], b[4];
#pragma unroll
    for (int mt = 0; mt < 4; mt++)
      a[mt] = *(const short8*)&As[cur + (wm + mt * 16 + l15) * 32 + quad * 8];
#pragma unroll
    for (int ntt = 0; ntt < 4; ntt++)
      b[ntt] = *(const short8*)&Bs[cur + (wn + ntt * 16 + l15) * 32 + quad * 8];
#pragma unroll
    for (int mt = 0; mt < 4; mt++)
#pragma unroll
      for (int ntt = 0; ntt < 4; ntt++)
        acc[mt][ntt] = MFMA_BF16(a[mt], b[ntt], acc[mt][ntt]);
    __syncthreads();   // drains vmcnt(0): prefetched tile becomes visible
  }
#pragma unroll
  for (int mt = 0; mt < 4; mt++) {
    int r0 = m0 + wm + mt * 16 + quad * 4;
#pragma unroll
    for (int nt2 = 0; nt2 < 4; nt2++) {
      int cc = n0 + wn + nt2 * 16 + l15;
#pragma unroll
      for (int rg = 0; rg < 4; rg++)
        C[(i64)(r0 + rg) * ldc + cc] = acc[mt][nt2][rg];
    }
  }
}

__global__ __launch_bounds__(256) void gemm_bt_kernel(
    const u16t* __restrict__ A, const u16t* __restrict__ B,
    float* __restrict__ C, int K, int ldc) {
  __shared__ u16t As[2 * 128 * 32];
  __shared__ u16t Bs[2 * 128 * 32];
  gemm_bt_body(A, B, C, K, ldc, blockIdx.x * 128, blockIdx.y * 128, As, Bs);
}

// ---------------- fused causal depthwise conv (K=4) + silu, VECTORIZED x4 ----------------
__global__ __launch_bounds__(256) void conv_silu3_kernel(
    const float* __restrict__ pre, const float* __restrict__ qw,
    const float* __restrict__ kw, const float* __restrict__ vw,
    float* __restrict__ qo, float* __restrict__ ko, float* __restrict__ vo,
    u16t* __restrict__ brcat) {
  int seg = blockIdx.x >> 11;          // 3 segs x 2048 rows
  int row = blockIdx.x & 2047;         // b*1024 + l
  int l = row & 1023;
  int c = threadIdx.x * 4;
  const float* w = seg == 0 ? qw : seg == 1 ? kw : vw;
  float* out = seg == 0 ? qo : seg == 1 ? ko : vo;
  float4 w0 = *(const float4*)(w + (i64)(c + 0) * 4);
  float4 w1 = *(const float4*)(w + (i64)(c + 1) * 4);
  float4 w2 = *(const float4*)(w + (i64)(c + 2) * 4);
  float4 w3 = *(const float4*)(w + (i64)(c + 3) * 4);
  const float* base = pre + (i64)row * 3072 + (seg << 10) + c;
  float4 x0 = *(const float4*)(base);
  float4 acc;
  acc.x = w0.w * x0.x; acc.y = w1.w * x0.y; acc.z = w2.w * x0.z; acc.w = w3.w * x0.w;
  if (l >= 1) {
    float4 xm = *(const float4*)(base - 3072);
    acc.x += w0.z * xm.x; acc.y += w1.z * xm.y; acc.z += w2.z * xm.z; acc.w += w3.z * xm.w;
  }
  if (l >= 2) {
    float4 xm = *(const float4*)(base - 2 * 3072);
    acc.x += w0.y * xm.x; acc.y += w1.y * xm.y; acc.z += w2.y * xm.z; acc.w += w3.y * xm.w;
  }
  if (l >= 3) {
    float4 xm = *(const float4*)(base - 3 * 3072);
    acc.x += w0.x * xm.x; acc.y += w1.x * xm.y; acc.z += w2.x * xm.z; acc.w += w3.x * xm.w;
  }
  float4 r;
  r.x = acc.x * sigmoidf_(acc.x);
  r.y = acc.y * sigmoidf_(acc.y);
  r.z = acc.z * sigmoidf_(acc.z);
  r.w = acc.w * sigmoidf_(acc.w);
  *(float4*)(out + (i64)row * 1024 + c) = r;
  if (seg == 2) {
    uint2 o;
    o.x = cvt_pk_bf16(r.x, r.y);
    o.y = cvt_pk_bf16(r.z, r.w);
    *(uint2*)(brcat + ((i64)row * 4 + (c >> 8)) * 1024 + 768 + (c & 255)) = o;
  }
}

// ---------------- preprocess: WAVE-PER-ROW, float4 (G13) ----------------
__global__ __launch_bounds__(256) void preprocess_kernel(
    const float* __restrict__ q, const float* __restrict__ k, const float* __restrict__ v,
    const float* __restrict__ beta, float* __restrict__ qn, float* __restrict__ kn,
    float* __restrict__ vb, float* __restrict__ kb, u16t* __restrict__ qnbf) {
  int t = threadIdx.x, lane = t & 63, wv = t >> 6;
  int row = blockIdx.x * 4 + wv;       // (b*1024+l)*4+h
  i64 base = (i64)row * 256 + lane * 4;
  float4 q4 = *(const float4*)(q + base);
  float4 k4 = *(const float4*)(k + base);
  float4 v4 = *(const float4*)(v + base);
  float s2[2];
  s2[0] = q4.x * q4.x + q4.y * q4.y + q4.z * q4.z + q4.w * q4.w;
  s2[1] = k4.x * k4.x + k4.y * k4.y + k4.z * k4.z + k4.w * k4.w;
#pragma unroll
  for (int off = 1; off < 64; off <<= 1) {
    s2[0] += __shfl_xor(s2[0], off);
    s2[1] += __shfl_xor(s2[1], off);
  }
  float qi = rsqrtf(s2[0] + 1e-6f), ki = rsqrtf(s2[1] + 1e-6f);
  float bet = beta[row];
  float4 qn4, kn4, vb4, kb4;
  qn4.x = q4.x * qi; qn4.y = q4.y * qi; qn4.z = q4.z * qi; qn4.w = q4.w * qi;
  kn4.x = k4.x * ki; kn4.y = k4.y * ki; kn4.z = k4.z * ki; kn4.w = k4.w * ki;
  vb4.x = v4.x * bet; vb4.y = v4.y * bet; vb4.z = v4.z * bet; vb4.w = v4.w * bet;
  kb4.x = kn4.x * bet; kb4.y = kn4.y * bet; kb4.z = kn4.z * bet; kb4.w = kn4.w * bet;
  *(float4*)(qn + base) = qn4;
  *(float4*)(kn + base) = kn4;
  *(float4*)(vb + base) = vb4;
  *(float4*)(kb + base) = kb4;
  int b = row >> 12, l = (row >> 2) & 1023, h = row & 3;
  uint2 o;
  o.x = cvt_pk_bf16(qn4.x, qn4.y);
  o.y = cvt_pk_bf16(qn4.z, qn4.w);
  *(uint2*)(qnbf + ((i64)(b * 4 + h) * 1024 + l) * 256 + lane * 4) = o;
}

// ---------------- phaseA2: phaseA(256) + W1/Wo transposes(2048) + wsum(24) ----
__global__ __launch_bounds__(256) void phaseA2_kernel(
    const float* __restrict__ qn, const float* __restrict__ kn,
    const float* __restrict__ vb, const float* __restrict__ kb,
    float* __restrict__ u_g, u16t* __restrict__ w_bf, u16t* __restrict__ attn_bf,
    u16t* __restrict__ knT,
    const float* __restrict__ gW1, const float* __restrict__ Wo,
    u16t* __restrict__ W1hT, u16t* __restrict__ W1bT, u16t* __restrict__ WoT,
    float* __restrict__ wsum) {
  __shared__ __attribute__((aligned(16))) char smem[37376];
  int blk = blockIdx.x, t = threadIdx.x;
  if (blk < 256) {
    float (*KN)[260] = (float(*)[260])smem;          // 33280 B
    float (*Ms)[32] = (float(*)[32])(smem + 33280);  // 4096 B
    int i = blk & 31, bh = blk >> 5;
    int rbase = ((bh >> 2) * LL + i * 32) * NH + (bh & 3);
    i64 bhn = blk;
#pragma unroll
    for (int ii = 0; ii < 8; ii++) {
      int fid = t + ii * 256;
      int c = fid >> 6, dq = (fid & 63) << 2;
      *(float4*)&KN[c][dq] = *(const float4*)(kn + (i64)(rbase + c * NH) * 256 + dq);
    }
    __syncthreads();
    int c = t >> 3, e0 = (t & 7) * 4;
    const float* kbp = kb + (i64)(rbase + c * NH) * 256;
    const float* qp = qn + (i64)(rbase + c * NH) * 256;
    float am[4] = {0, 0, 0, 0}, aa[4] = {0, 0, 0, 0};
    for (int d = 0; d < 256; d += 4) {
      float4 kv = *(const float4*)(kbp + d);
      float4 qv = *(const float4*)(qp + d);
#pragma unroll
      for (int z = 0; z < 4; z++) {
        float4 nv = *(const float4*)&KN[e0 + z][d];
        am[z] += kv.x * nv.x + kv.y * nv.y + kv.z * nv.z + kv.w * nv.w;
        aa[z] += qv.x * nv.x + qv.y * nv.y + qv.z * nv.z + qv.w * nv.w;
      }
    }
    {
      uint2 o;
      u16t a0 = (e0 + 0 <= c) ? f2bf(aa[0]) : 0;
      u16t a1 = (e0 + 1 <= c) ? f2bf(aa[1]) : 0;
      u16t a2 = (e0 + 2 <= c) ? f2bf(aa[2]) : 0;
      u16t a3 = (e0 + 3 <= c) ? f2bf(aa[3]) : 0;
      o.x = pk2(a0, a1); o.y = pk2(a2, a3);
      *(uint2*)(attn_bf + bhn * 1024 + c * 32 + e0) = o;
    }
#pragma unroll
    for (int z = 0; z < 4; z++) {
      int e = e0 + z;
      Ms[c][e] = (e < c) ? am[z] : 0.0f;
    }
    __syncthreads();
    float uc[32], wc[32];
#pragma unroll
    for (int cc = 0; cc < 32; cc++) {
      float uval = vb[(i64)(rbase + cc * NH) * 256 + t];
      float wval = kb[(i64)(rbase + cc * NH) * 256 + t];
#pragma unroll
      for (int c2 = 0; c2 < cc; c2++) {
        float m = Ms[cc][c2];
        uval -= m * uc[c2];
        wval -= m * wc[c2];
      }
      uc[cc] = uval; wc[cc] = wval;
      u_g[(bhn * 32 + cc) * 256 + t] = uval;
      w_bf[(bhn * 32 + cc) * 256 + t] = f2bf(-wval);
    }
    int d = t;
    u16t o[32];
#pragma unroll
    for (int cc = 0; cc < 32; cc++) o[cc] = f2bf(KN[cc][d]);
#pragma unroll
    for (int z = 0; z < 4; z++) {
      uint4 vv;
      vv.x = pk2(o[z * 8 + 0], o[z * 8 + 1]);
      vv.y = pk2(o[z * 8 + 2], o[z * 8 + 3]);
      vv.z = pk2(o[z * 8 + 4], o[z * 8 + 5]);
      vv.w = pk2(o[z * 8 + 6], o[z * 8 + 7]);
      *(uint4*)(knT + (bhn * 256 + d) * 32 + z * 8) = vv;
    }
  } else if (blk < 2304) {
    float (*tile)[33] = (float(*)[33])smem;
    int pb = blk - 256;
    if (pb < 1024) {
      int which = pb >> 9, bi = pb & 511;
      const float* in = gW1 + (which ? (i64)4096 * 512 : 0);
      transcast_body(in, 512, which ? W1bT : W1hT, 1024, bi & 15, bi >> 4, tile);
    } else {
      int bi = pb - 1024;
      transcast_body(Wo, 1024, WoT, 1024, bi & 31, bi >> 5, tile);
    }
  } else {
    int bi = blk - 2304;         // 24 blocks: 12 stats x 2 col-halves
    int s12 = bi >> 1, col = (bi & 1) * 256 + t;
    const float* p = gW1 + (i64)(1024 + s12 * 256) * 512 + col;
    float acc = 0.0f;
    for (int r = 0; r < 256; r++) acc += p[(i64)r * 512];
    wsum[s12 * 512 + col] = acc;
  }
}

// ---------------- delta scan body (verbatim passing version) ----------------
#define SROW 264
struct ScanBuf {
  short8 m8[8];
  f32x4 uc4;
  short8 af;
  short8 kf[4];
};

__device__ void delta_scan_body(
    int blk,
    const u16t* __restrict__ wbf, const u16t* __restrict__ knT,
    const float* __restrict__ u_g, const u16t* __restrict__ qnbf,
    const u16t* __restrict__ attnbf,
    float* __restrict__ dlt, u16t* __restrict__ brcat,
    u16t* Sbf, u16t* Ubf) {
  int t = threadIdx.x, w = t >> 6, lane = t & 63;
  int l15 = lane & 15, quad = lane >> 4;
  int bh = blk & 7, jb = blk >> 3, j0 = jb * 16;
  int b_ = bh >> 2, h_ = bh & 3;
  bool isU = (w < 2);
  int wc = isU ? w : (w - 2);
  for (int idx = t; idx < 16 * SROW; idx += 256) Sbf[idx] = 0;
  f32x4 accS[4] = {};
  __syncthreads();
  __builtin_amdgcn_s_setprio(1);

  auto load_chunk = [&](int i, ScanBuf& B) {
    i64 bhn = (i64)bh * 32 + i;
    const u16t* mbase = isU
        ? wbf + (bhn * 32 + wc * 16 + l15) * 256 + quad * 8
        : qnbf + ((i64)bh * 1024 + i * 32 + wc * 16 + l15) * 256 + quad * 8;
#pragma unroll
    for (int kd = 0; kd < 8; kd++) B.m8[kd] = *(const short8*)(mbase + kd * 32);
    if (isU) {
      int cm = wc * 16 + quad * 4;
#pragma unroll
      for (int r = 0; r < 4; r++)
        B.uc4[r] = u_g[(bhn * 32 + cm + r) * 256 + j0 + l15];
    } else {
      B.af = *(const short8*)(attnbf + bhn * 1024 + (wc * 16 + l15) * 32 + quad * 8);
    }
#pragma unroll
    for (int dt = 0; dt < 4; dt++)
      B.kf[dt] = *(const short8*)(knT + (bhn * 256 + w * 64 + dt * 16 + l15) * 32 + quad * 8);
  };

  auto process = [&](int i, ScanBuf& B) {
    f32x4 zero = {};
    f32x4 ca = isU ? B.uc4 : zero;
    f32x4 cb = zero;
#pragma unroll
    for (int kd = 0; kd < 4; kd++) {
      short8 sfa = *(const short8*)&Sbf[l15 * SROW + kd * 32 + quad * 8];
      short8 sfb = *(const short8*)&Sbf[l15 * SROW + (kd + 4) * 32 + quad * 8];
      ca = MFMA_BF16(B.m8[kd], sfa, ca);
      cb = MFMA_BF16(B.m8[kd + 4], sfb, cb);
    }
    f32x4 cacc;
#pragma unroll
    for (int r = 0; r < 4; r++) cacc[r] = ca[r] + cb[r];
    if (isU) {
      int cm = wc * 16 + quad * 4;
      uint2 o;
      o.x = cvt_pk_bf16(cacc[0], cacc[1]);
      o.y = cvt_pk_bf16(cacc[2], cacc[3]);
      *(uint2*)&Ubf[l15 * 40 + cm] = o;
    }
    barrier_lds_only();
    short8 bu = *(const short8*)&Ubf[l15 * 40 + quad * 8];
    if (!isU) {
      cacc = MFMA_BF16(B.af, bu, cacc);
#pragma unroll
      for (int rg = 0; rg < 4; rg++) {
        int l = i * 32 + wc * 16 + quad * 4 + rg;
        i64 row = ((i64)b_ * 1024 + l) * 4 + h_;
        dlt[row * 256 + j0 + l15] = cacc[rg];
        brcat[row * 1024 + 512 + j0 + l15] = f2bf(cacc[rg]);
      }
    }
#pragma unroll
    for (int dt = 0; dt < 4; dt++) accS[dt] = MFMA_BF16(B.kf[dt], bu, accS[dt]);
#pragma unroll
    for (int dt = 0; dt < 4; dt++) {
      uint2 o;
      o.x = cvt_pk_bf16(accS[dt][0], accS[dt][1]);
      o.y = cvt_pk_bf16(accS[dt][2], accS[dt][3]);
      *(uint2*)&Sbf[l15 * SROW + w * 64 + dt * 16 + quad * 4] = o;
    }
    barrier_lds_only();
  };

  ScanBuf b0, b1;
  load_chunk(0, b0);
#pragma unroll 1
  for (int ii = 0; ii < 16; ii++) {
    int i = ii * 2;
    load_chunk(i + 1, b1);
    process(i, b0);
    if (ii < 15) load_chunk(i + 2, b0);
    process(i + 1, b1);
  }
  __builtin_amdgcn_s_setprio(0);
}

// ---------------- FIR body ----------------
__device__ void fir2_body(
    int blk, const float* __restrict__ v,
    const float* __restrict__ f_s, const float* __restrict__ f_l,
    float* __restrict__ fs, float* __restrict__ fl, u16t* __restrict__ brcat) {
  int t = threadIdx.x;
  int b = blk >> 8, h = (blk >> 6) & 3, lc = blk & 63;
  int l0 = lc * 16;
  float flw[31], fsw[3];
  const float* flp = f_l + ((i64)h * 256 + t) * 31;
#pragma unroll
  for (int j = 0; j < 31; j++) flw[j] = flp[j];
  const float* fsp = f_s + ((i64)h * 256 + t) * 3;
#pragma unroll
  for (int j = 0; j < 3; j++) fsw[j] = fsp[j];
  float win[46];
#pragma unroll
  for (int r = 0; r < 46; r++) {
    int l = l0 - 30 + r;
    win[r] = (l >= 0) ? v[(((i64)b * 1024 + l) * 4 + h) * 256 + t] : 0.0f;
  }
#pragma unroll
  for (int i = 0; i < 16; i++) {
    float al = 0.0f;
#pragma unroll
    for (int j = 0; j < 31; j++) al += flw[j] * win[i + j];
    float as = fsw[0] * win[i + 28] + fsw[1] * win[i + 29] + fsw[2] * win[i + 30];
    i64 row = ((i64)b * 1024 + (l0 + i)) * 4 + h;
    fs[row * 256 + t] = as;
    fl[row * 256 + t] = al;
    brcat[row * 1024 + t] = f2bf(as);
    brcat[row * 1024 + 256 + t] = f2bf(al);
  }
}

// ---------------- mega5: scan(128) + fir(512) + hbase gemm(64) ----------------
__global__ __launch_bounds__(256) void mega5_kernel(
    const u16t* __restrict__ wbf, const u16t* __restrict__ knT,
    const float* __restrict__ u_g, const u16t* __restrict__ qnbf,
    const u16t* __restrict__ attnbf, float* __restrict__ dlt, u16t* __restrict__ brcat,
    const float* __restrict__ vbuf, const float* __restrict__ firs,
    const float* __restrict__ firl, float* __restrict__ fs, float* __restrict__ fl,
    const u16t* __restrict__ xbf, const u16t* __restrict__ W1hT,
    float* __restrict__ hbase) {
  __shared__ __attribute__((aligned(16))) char smem[32768];
  int blk = blockIdx.x;
  if (blk < 128) {
    u16t* Sbf = (u16t*)smem;
    u16t* Ubf = Sbf + 16 * SROW;
    delta_scan_body(blk, wbf, knT, u_g, qnbf, attnbf, dlt, brcat, Sbf, Ubf);
  } else if (blk < 640) {
    fir2_body(blk - 128, vbuf, firs, firl, fs, fl, brcat);
  } else {
    int bi = blk - 640;
    u16t* As = (u16t*)smem;             // 2*128*32 u16 = 16384 B
    u16t* Bs = As + 2 * 128 * 32;       // next 16384 B
    gemm_bt_body(xbf, W1hT, hbase, 1024, 512, (bi & 3) * 128, (bi >> 2) * 128, As, Bs);
  }
}

// ---------------- gate MLP tail + mix + RMS norm: WAVE-PER-ROW ----------------
__global__ __launch_bounds__(256) void gatemix_kernel(
    const float* __restrict__ hbase, const float* __restrict__ brW,
    const float* __restrict__ wsum,
    const float* __restrict__ gb1, const float* __restrict__ gW2,
    const float* __restrict__ gb2, const float* __restrict__ temp,
    const float* __restrict__ epsf,
    const float* __restrict__ fs, const float* __restrict__ fl,
    const float* __restrict__ dlt, const float* __restrict__ v,
    const float* __restrict__ onw, u16t* __restrict__ out) {
  int t = threadIdx.x, lane = t & 63, wv = t >> 6;
  int row = blockIdx.x * 4 + wv;      // (b*1024+l)*4+h
  int bl = row >> 2, h = row & 3;
  i64 base = (i64)row * 256 + lane * 4;
  float4 vfs = *(const float4*)(fs + base);
  float4 vfl = *(const float4*)(fl + base);
  float4 vdl = *(const float4*)(dlt + base);
  float4 vvv = *(const float4*)(v + base);
  float r8[8];
  r8[0] = vfs.x + vfs.y + vfs.z + vfs.w;
  r8[1] = vfs.x * vfs.x + vfs.y * vfs.y + vfs.z * vfs.z + vfs.w * vfs.w;
  r8[2] = vfl.x + vfl.y + vfl.z + vfl.w;
  r8[3] = vfl.x * vfl.x + vfl.y * vfl.y + vfl.z * vfl.z + vfl.w * vfl.w;
  r8[4] = vdl.x + vdl.y + vdl.z + vdl.w;
  r8[5] = vdl.x * vdl.x + vdl.y * vdl.y + vdl.z * vdl.z + vdl.w * vdl.w;
  r8[6] = vvv.x + vvv.y + vvv.z + vvv.w;
  r8[7] = vvv.x * vvv.x + vvv.y * vvv.y + vvv.z * vvv.z + vvv.w * vvv.w;
#pragma unroll
  for (int off = 1; off < 64; off <<= 1) {
#pragma unroll
    for (int i = 0; i < 8; i++) r8[i] += __shfl_xor(r8[i], off);
  }
  float m4[4];
  m4[0] = fmaxf(fmaxf(vfs.x, vfs.y), fmaxf(vfs.z, vfs.w));
  m4[1] = fmaxf(fmaxf(vfl.x, vfl.y), fmaxf(vfl.z, vfl.w));
  m4[2] = fmaxf(fmaxf(vdl.x, vdl.y), fmaxf(vdl.z, vdl.w));
  m4[3] = fmaxf(fmaxf(vvv.x, vvv.y), fmaxf(vvv.z, vvv.w));
#pragma unroll
  for (int off = 1; off < 64; off <<= 1) {
#pragma unroll
    for (int i = 0; i < 4; i++) m4[i] = fmaxf(m4[i], __shfl_xor(m4[i], off));
  }
  float st[12];
#pragma unroll
  for (int p = 0; p < 4; p++) {
    st[p * 3 + 0] = r8[p * 2] * (1.0f / 256.0f);
    st[p * 3 + 1] = sqrtf(fmaxf(r8[p * 2 + 1] * (1.0f / 256.0f), 1e-8f));
    st[p * 3 + 2] = m4[p];
  }
  float lg[4] = {0, 0, 0, 0};
#pragma unroll
  for (int jj = 0; jj < 8; jj++) {
    int o = jj * 64 + lane;
    float hm = hbase[(i64)bl * 512 + o] + brW[(i64)row * 512 + o] + gb1[o];
#pragma unroll
    for (int s = 0; s < 12; s++) hm += st[s] * wsum[s * 512 + o];
    float ge = 0.5f * hm * (1.0f + erff(hm * 0.70710678118654752f));
    float4 w2 = *(const float4*)(gW2 + o * 4);
    lg[0] += ge * w2.x; lg[1] += ge * w2.y; lg[2] += ge * w2.z; lg[3] += ge * w2.w;
  }
#pragma unroll
  for (int off = 1; off < 64; off <<= 1) {
#pragma unroll
    for (int i = 0; i < 4; i++) lg[i] += __shfl_xor(lg[i], off);
  }
  float tt = fminf(fmaxf(temp[h], 0.2f), 10.0f);
  float l0 = (lg[0] + gb2[0]) / tt;
  float l1 = (lg[1] + gb2[1]) / tt;
  float l2 = (lg[2] + gb2[2]) / tt;
  float l3 = (lg[3] + gb2[3]) / tt;
  float m = fmaxf(fmaxf(l0, l1), fmaxf(l2, l3));
  float e0 = expf(l0 - m), e1 = expf(l1 - m), e2 = expf(l2 - m), e3 = expf(l3 - m);
  float ssum = e0 + e1 + e2 + e3;
  float w0 = e0 / ssum, w1 = e1 / ssum, w2 = e2 / ssum, w3 = e3 / ssum;
  w0 = fmaxf(w0, fminf(fmaxf(epsf[h * 4 + 0], 1e-7f), 0.1f));
  w1 = fmaxf(w1, fminf(fmaxf(epsf[h * 4 + 1], 1e-7f), 0.1f));
  w2 = fmaxf(w2, fminf(fmaxf(epsf[h * 4 + 2], 1e-7f), 0.1f));
  w3 = fmaxf(w3, fminf(fmaxf(epsf[h * 4 + 3], 1e-7f), 0.1f));
  float s2 = w0 + w1 + w2 + w3;
  float g0 = w0 / s2, g1 = w1 / s2, g2 = w2 / s2, g3 = w3 / s2;
  float4 o4;
  o4.x = g0 * vfs.x + g1 * vfl.x + g2 * vdl.x + g3 * vvv.x;
  o4.y = g0 * vfs.y + g1 * vfl.y + g2 * vdl.y + g3 * vvv.y;
  o4.z = g0 * vfs.z + g1 * vfl.z + g2 * vdl.z + g3 * vvv.z;
  o4.w = g0 * vfs.w + g1 * vfl.w + g2 * vdl.w + g3 * vvv.w;
  float ss = o4.x * o4.x + o4.y * o4.y + o4.z * o4.z + o4.w * o4.w;
#pragma unroll
  for (int off = 1; off < 64; off <<= 1) ss += __shfl_xor(ss, off);
  float scale = rsqrtf(ss * (1.0f / 256.0f) + 1e-5f);
  float4 ow4 = *(const float4*)(onw + lane * 4);
  uint2 ow;
  ow.x = cvt_pk_bf16(o4.x * scale * ow4.x, o4.y * scale * ow4.y);
  ow.y = cvt_pk_bf16(o4.z * scale * ow4.z, o4.w * scale * ow4.w);
  *(uint2*)(out + (i64)bl * 1024 + h * 256 + lane * 4) = ow;
}

extern "C" void kernel_launch(void* const* d_in, const int* in_sizes, int n_in,
                              void* d_out, int out_size, void* d_ws, size_t ws_size,
                              hipStream_t stream) {
  (void)in_sizes; (void)n_in; (void)out_size; (void)ws_size;
  const float* x    = (const float*)d_in[0];
  const float* Wq   = (const float*)d_in[1];
  const float* Wk   = (const float*)d_in[2];
  const float* Wv   = (const float*)d_in[3];
  const float* Wb   = (const float*)d_in[4];
  const float* qcw  = (const float*)d_in[5];
  const float* kcw  = (const float*)d_in[6];
  const float* vcw  = (const float*)d_in[7];
  const float* gW1  = (const float*)d_in[8];
  const float* gb1  = (const float*)d_in[9];
  const float* gW2  = (const float*)d_in[10];
  const float* gb2  = (const float*)d_in[11];
  const float* temp = (const float*)d_in[12];
  const float* epsf = (const float*)d_in[13];
  const float* onw  = (const float*)d_in[14];
  const float* Wo   = (const float*)d_in[15];
  const float* firs = (const float*)d_in[16];
  const float* firl = (const float*)d_in[17];
  float* out = (float*)d_out;

  float* ws = (float*)d_ws;
  // ---- workspace map (float offsets) ----
  float* qkv_pre  = ws + 0;                       // 2048*3072 fp32 (dead after conv)
  float* branchW  = ws + 0;                       // 8192*512 fp32 (step 7+)
  float* hbase    = ws + 4194304;                 // 2048*512 fp32 (step 6+)
  u16t*  W1hT     = (u16t*)(ws + 5242880);        // 512x1024 bf16 (step 5+)
  u16t*  W1bT     = (u16t*)(ws + 5505024);        // 512x1024 bf16
  u16t*  WoT      = (u16t*)(ws + 5767168);        // 1024x1024 bf16
  u16t*  brcat    = (u16t*)(ws + 6291456);        // 8192*1024 bf16
  float* qbuf     = ws + 10485760; float* qn = qbuf;
  float* kbuf     = ws + 12582912; float* kn = kbuf;
  float* vbuf     = ws + 14680064;
  float* vb       = ws + 16777216;                // dead after phaseA2
  u16t*  omix_bf  = (u16t*)(ws + 16777216);       // gatemix+ (2048*1024 bf16)
  float* kb       = ws + 18874368;                // dead after phaseA2
  float* dlt      = ws + 18874368;                // scan output
  float* u_g      = ws + 20971520;
  u16t*  w_bf     = (u16t*)(ws + 23068672);
  u16t*  qn_bf    = (u16t*)(ws + 24117248);
  u16t*  knT      = (u16t*)(ws + 25165824);
  u16t*  attn_bf  = (u16t*)(ws + 26214400);
  float* fs       = ws + 26345472;
  float* fl       = ws + 28442624;
  u16t*  xbf      = (u16t*)(ws + 30539776);
  u16t*  WqkvT    = (u16t*)(ws + 31588352);
  float* betab    = ws + 33161216;                // 8192 fp32
  float* wsum     = ws + 33267712;

  // 1) prep: QKV weight transpose + x cast + beta
  prep_kernel<<<7168, 256, 0, stream>>>(Wq, Wk, Wv, x, Wb, WqkvT, xbf, betab);
  // 2) QKV GEMM (2-phase dbuf global_load_lds staging)
  gemm_bt_kernel<<<dim3(24, 16), 256, 0, stream>>>(xbf, WqkvT, qkv_pre, 1024, 3072);
  // 3) conv+silu vectorized x4 (v also -> brcat col 768); kills qkv_pre
  conv_silu3_kernel<<<6144, 256, 0, stream>>>(qkv_pre, qcw, kcw, vcw, qbuf, kbuf, vbuf, brcat);
  // 4) preprocess (wave-per-row, float4)
  preprocess_kernel<<<2048, 256, 0, stream>>>(qbuf, kbuf, vbuf, betab, qn, kn, vb, kb, qn_bf);
  // 5) phaseA2: UT-transform + W1/Wo transposes (into dead qkv_pre) + wsum
  phaseA2_kernel<<<2328, 256, 0, stream>>>(qn, kn, vb, kb, u_g, w_bf, attn_bf, knT,
                                           gW1, Wo, W1hT, W1bT, WoT, wsum);
  // 6) mega5: scan + FIR + hbase GEMM
  mega5_kernel<<<704, 256, 0, stream>>>(w_bf, knT, u_g, qn_bf, attn_bf, dlt, brcat,
                                        vbuf, firs, firl, fs, fl,
                                        xbf, W1hT, hbase);
  // 7) branchW GEMM
  gemm_bt_kernel<<<dim3(4, 64), 256, 0, stream>>>(brcat, W1bT, branchW, 1024, 512);
  // 8) gate tail + mix + RMS (wave-per-row, no barriers)
  gatemix_kernel<<<2048, 256, 0, stream>>>(hbase, branchW, wsum, gb1, gW2, gb2,
                                           temp, epsf, fs, fl, dlt, vbuf, onw, omix_bf);
  // 9) final projection
  gemm_bt_kernel<<<dim3(8, 16), 256, 0, stream>>>(omix_bf, WoT, out, 1024, 1024);
}

// Round 12
// 313.925 us; speedup vs baseline: 1.0919x; 1.0085x over previous
//
#include <hip/hip_runtime.h>
#include <math.h>

// Problem constants
#define BB 2
#define LL 1024
#define HIDD 1024
#define NH 4
#define DD 256
#define NCH 32
#define ROWS 2048
#define HROWS 8192

typedef long long i64;
typedef unsigned short u16t;
typedef unsigned int u32t;
typedef __attribute__((ext_vector_type(8))) short short8;
typedef __attribute__((ext_vector_type(4))) float f32x4;
#define MFMA_BF16(a, b, c) __builtin_amdgcn_mfma_f32_16x16x32_bf16(a, b, c, 0, 0, 0)

__device__ __forceinline__ float sigmoidf_(float x) { return 1.0f / (1.0f + expf(-x)); }

__device__ __forceinline__ u16t f2bf(float f) {
  u32t u = __float_as_uint(f);
  u = u + 0x7FFFu + ((u >> 16) & 1u);
  return (u16t)(u >> 16);
}
__device__ __forceinline__ u32t pk2(u16t a, u16t b) { return (u32t)a | ((u32t)b << 16); }

// HW packed f32->bf16 RNE convert (gfx950): 1 instr vs 6-op bit-trick pair.
__device__ __forceinline__ u32t cvt_pk_bf16(float lo, float hi) {
  u32t r;
  asm("v_cvt_pk_bf16_f32 %0, %1, %2" : "=v"(r) : "v"(lo), "v"(hi));
  return r;
}

// async global->LDS, 16B per lane (wave-uniform LDS base, per-lane global src).
__device__ __forceinline__ void async_load16(const u16t* g, u16t* l) {
  __builtin_amdgcn_global_load_lds(
      (const __attribute__((address_space(1))) u32t*)g,
      (__attribute__((address_space(3))) u32t*)l, 16, 0, 0);
}

// counted-wait barrier: drain only LDS ops, keep global loads in flight.
__device__ __forceinline__ void barrier_lds_only() {
  asm volatile("s_waitcnt lgkmcnt(0)" ::: "memory");
  __builtin_amdgcn_s_barrier();
  asm volatile("" ::: "memory");
}

// ---------------- block reduction helper (blockDim == 256) ----------------
template<int N>
__device__ __forceinline__ void block_reduce_sum(float* v, float* scratch) {
  int lane = threadIdx.x & 63, wid = threadIdx.x >> 6;
#pragma unroll
  for (int i = 0; i < N; i++) {
    float x = v[i];
#pragma unroll
    for (int off = 1; off < 64; off <<= 1) x += __shfl_xor(x, off);
    if (lane == 0) scratch[wid * N + i] = x;
  }
  __syncthreads();
#pragma unroll
  for (int i = 0; i < N; i++)
    v[i] = scratch[i] + scratch[N + i] + scratch[2 * N + i] + scratch[3 * N + i];
  __syncthreads();
}

// ---------------- transpose+cast body: fp32 [K][N] -> bf16 [N][K], one 32x32 tile ----------------
__device__ __forceinline__ void transcast_body(
    const float* __restrict__ in, int ldin, u16t* __restrict__ out, int ldout,
    int nbi, int kbi, float (*tile)[33]) {
  int tx = threadIdx.x & 31, ty = threadIdx.x >> 5;
  int nb = nbi * 32, kb = kbi * 32;
#pragma unroll
  for (int r = 0; r < 4; r++)
    tile[ty + r * 8][tx] = in[(i64)(kb + ty + r * 8) * ldin + nb + tx];
  __syncthreads();
#pragma unroll
  for (int r = 0; r < 4; r++)
    out[(i64)(nb + ty + r * 8) * ldout + kb + tx] = f2bf(tile[tx][ty + r * 8]);
}

// ---------------- prep (step 1): WqkvT(3072) + xbf(2048) + beta(2048) ----------------
__global__ __launch_bounds__(256) void prep_kernel(
    const float* __restrict__ Wq, const float* __restrict__ Wk, const float* __restrict__ Wv,
    const float* __restrict__ x, const float* __restrict__ Wb,
    u16t* __restrict__ WqkvT, u16t* __restrict__ xbf, float* __restrict__ betab) {
  __shared__ float tile[32][33];
  int blk = blockIdx.x, t = threadIdx.x;
  if (blk < 3072) {
    int m = blk >> 10, bi = blk & 1023;
    const float* in = m == 0 ? Wq : m == 1 ? Wk : Wv;
    transcast_body(in, 1024, WqkvT + (i64)m * 1024 * 1024, 1024, bi & 31, bi >> 5, tile);
  } else if (blk < 5120) {
    i64 e = ((i64)(blk - 3072) * 256 + t) * 4;
    float4 v = *(const float4*)(x + e);
    uint2 o;
    o.x = pk2(f2bf(v.x), f2bf(v.y));
    o.y = pk2(f2bf(v.z), f2bf(v.w));
    *(uint2*)(xbf + e) = o;
  } else {
    int row = blk - 5120;
    float a[4] = {0, 0, 0, 0};
    for (int c = t; c < 1024; c += 256) {
      float xv = x[(i64)row * 1024 + c];
      float4 wv = *(const float4*)(Wb + c * 4);
      a[0] += xv * wv.x; a[1] += xv * wv.y; a[2] += xv * wv.z; a[3] += xv * wv.w;
    }
    block_reduce_sum<4>(a, (float*)tile);
    if (t == 0) {
#pragma unroll
      for (int g = 0; g < 4; g++) betab[row * 4 + g] = sigmoidf_(a[g]);
    }
  }
}

// ---------------- K-range accumulating GEMM tiles (2-phase dbuf, async LDS) ----
// Processes Kext cols (mult of 32) starting at koff of A[M][ld], B[N][ld],
// accumulating into acc. Entry & exit: all waves barrier-synced, buffers free.
__device__ __forceinline__ void gemm_tiles_acc(
    const u16t* __restrict__ A, const u16t* __restrict__ B,
    i64 ld, int koff, int Kext, int n0, int m0,
    u16t* As, u16t* Bs, f32x4 (&acc)[4][4]) {
  int t = threadIdx.x;
  int w = t >> 6, lane = t & 63;
  int l15 = lane & 15, quad = lane >> 4;
  int wm = (w & 1) * 64, wn = (w >> 1) * 64;
  int c0 = 2 * w, c1 = 2 * w + 1;
  int srow0 = c0 * 16 + (lane >> 2);
  int srow1 = c1 * 16 + (lane >> 2);
  int scol = (lane & 3) * 8;
  const u16t* Ag0 = A + (i64)(m0 + srow0) * ld + koff + scol;
  const u16t* Ag1 = A + (i64)(m0 + srow1) * ld + koff + scol;
  const u16t* Bg0 = B + (i64)(n0 + srow0) * ld + koff + scol;
  const u16t* Bg1 = B + (i64)(n0 + srow1) * ld + koff + scol;
  int lb0 = c0 * 512, lb1 = c1 * 512;   // wave-uniform LDS chunk bases
  async_load16(Ag0, As + lb0);
  async_load16(Ag1, As + lb1);
  async_load16(Bg0, Bs + lb0);
  async_load16(Bg1, Bs + lb1);
  __syncthreads();
  int nt = Kext >> 5;
  for (int ti = 0; ti < nt; ++ti) {
    int cur = (ti & 1) << 12;           // buffer offset (4096 u16)
    if (ti + 1 < nt) {
      int nxt = ((ti + 1) & 1) << 12;
      int k = (ti + 1) << 5;
      async_load16(Ag0 + k, As + nxt + lb0);
      async_load16(Ag1 + k, As + nxt + lb1);
      async_load16(Bg0 + k, Bs + nxt + lb0);
      async_load16(Bg1 + k, Bs + nxt + lb1);
    }
    short8 a[4], b[4];
#pragma unroll
    for (int mt = 0; mt < 4; mt++)
      a[mt] = *(const short8*)&As[cur + (wm + mt * 16 + l15) * 32 + quad * 8];
#pragma unroll
    for (int ntt = 0; ntt < 4; ntt++)
      b[ntt] = *(const short8*)&Bs[cur + (wn + ntt * 16 + l15) * 32 + quad * 8];
#pragma unroll
    for (int mt = 0; mt < 4; mt++)
#pragma unroll
      for (int ntt = 0; ntt < 4; ntt++)
        acc[mt][ntt] = MFMA_BF16(a[mt], b[ntt], acc[mt][ntt]);
    __syncthreads();   // drains vmcnt(0): prefetched tile becomes visible
  }
}

__device__ __forceinline__ void gemm_store(
    float* __restrict__ C, int ldc, int n0, int m0, f32x4 (&acc)[4][4], bool add) {
  int t = threadIdx.x;
  int w = t >> 6, lane = t & 63;
  int l15 = lane & 15, quad = lane >> 4;
  int wm = (w & 1) * 64, wn = (w >> 1) * 64;
#pragma unroll
  for (int mt = 0; mt < 4; mt++) {
    int r0 = m0 + wm + mt * 16 + quad * 4;
#pragma unroll
    for (int nt = 0; nt < 4; nt++) {
      int cc = n0 + wn + nt * 16 + l15;
#pragma unroll
      for (int rg = 0; rg < 4; rg++) {
        i64 idx = (i64)(r0 + rg) * ldc + cc;
        C[idx] = add ? (C[idx] + acc[mt][nt][rg]) : acc[mt][nt][rg];
      }
    }
  }
}

__device__ __forceinline__ void gemm_bt_body(
    const u16t* __restrict__ A, const u16t* __restrict__ B,
    float* __restrict__ C, int K, int ldc, int n0, int m0,
    u16t* As, u16t* Bs) {
  f32x4 acc[4][4] = {};
  gemm_tiles_acc(A, B, K, 0, K, n0, m0, As, Bs, acc);
  gemm_store(C, ldc, n0, m0, acc, false);
}

__global__ __launch_bounds__(256) void gemm_bt_kernel(
    const u16t* __restrict__ A, const u16t* __restrict__ B,
    float* __restrict__ C, int K, int ldc) {
  __shared__ u16t As[2 * 128 * 32];
  __shared__ u16t Bs[2 * 128 * 32];
  gemm_bt_body(A, B, C, K, ldc, blockIdx.x * 128, blockIdx.y * 128, As, Bs);
}

// ---------------- fused causal depthwise conv (K=4) + silu, VECTORIZED x4 ----------------
__global__ __launch_bounds__(256) void conv_silu3_kernel(
    const float* __restrict__ pre, const float* __restrict__ qw,
    const float* __restrict__ kw, const float* __restrict__ vw,
    float* __restrict__ qo, float* __restrict__ ko, float* __restrict__ vo,
    u16t* __restrict__ brcat) {
  int seg = blockIdx.x >> 11;          // 3 segs x 2048 rows
  int row = blockIdx.x & 2047;         // b*1024 + l
  int l = row & 1023;
  int c = threadIdx.x * 4;
  const float* w = seg == 0 ? qw : seg == 1 ? kw : vw;
  float* out = seg == 0 ? qo : seg == 1 ? ko : vo;
  float4 w0 = *(const float4*)(w + (i64)(c + 0) * 4);
  float4 w1 = *(const float4*)(w + (i64)(c + 1) * 4);
  float4 w2 = *(const float4*)(w + (i64)(c + 2) * 4);
  float4 w3 = *(const float4*)(w + (i64)(c + 3) * 4);
  const float* base = pre + (i64)row * 3072 + (seg << 10) + c;
  float4 x0 = *(const float4*)(base);
  float4 acc;
  acc.x = w0.w * x0.x; acc.y = w1.w * x0.y; acc.z = w2.w * x0.z; acc.w = w3.w * x0.w;
  if (l >= 1) {
    float4 xm = *(const float4*)(base - 3072);
    acc.x += w0.z * xm.x; acc.y += w1.z * xm.y; acc.z += w2.z * xm.z; acc.w += w3.z * xm.w;
  }
  if (l >= 2) {
    float4 xm = *(const float4*)(base - 2 * 3072);
    acc.x += w0.y * xm.x; acc.y += w1.y * xm.y; acc.z += w2.y * xm.z; acc.w += w3.y * xm.w;
  }
  if (l >= 3) {
    float4 xm = *(const float4*)(base - 3 * 3072);
    acc.x += w0.x * xm.x; acc.y += w1.x * xm.y; acc.z += w2.x * xm.z; acc.w += w3.x * xm.w;
  }
  float4 r;
  r.x = acc.x * sigmoidf_(acc.x);
  r.y = acc.y * sigmoidf_(acc.y);
  r.z = acc.z * sigmoidf_(acc.z);
  r.w = acc.w * sigmoidf_(acc.w);
  *(float4*)(out + (i64)row * 1024 + c) = r;
  if (seg == 2) {
    uint2 o;
    o.x = cvt_pk_bf16(r.x, r.y);
    o.y = cvt_pk_bf16(r.z, r.w);
    *(uint2*)(brcat + ((i64)row * 4 + (c >> 8)) * 1024 + 768 + (c & 255)) = o;
  }
}

// ---------------- preprocess: WAVE-PER-ROW, float4 (G13) ----------------
__global__ __launch_bounds__(256) void preprocess_kernel(
    const float* __restrict__ q, const float* __restrict__ k, const float* __restrict__ v,
    const float* __restrict__ beta, float* __restrict__ qn, float* __restrict__ kn,
    float* __restrict__ vb, float* __restrict__ kb, u16t* __restrict__ qnbf) {
  int t = threadIdx.x, lane = t & 63, wv = t >> 6;
  int row = blockIdx.x * 4 + wv;       // (b*1024+l)*4+h
  i64 base = (i64)row * 256 + lane * 4;
  float4 q4 = *(const float4*)(q + base);
  float4 k4 = *(const float4*)(k + base);
  float4 v4 = *(const float4*)(v + base);
  float s2[2];
  s2[0] = q4.x * q4.x + q4.y * q4.y + q4.z * q4.z + q4.w * q4.w;
  s2[1] = k4.x * k4.x + k4.y * k4.y + k4.z * k4.z + k4.w * k4.w;
#pragma unroll
  for (int off = 1; off < 64; off <<= 1) {
    s2[0] += __shfl_xor(s2[0], off);
    s2[1] += __shfl_xor(s2[1], off);
  }
  float qi = rsqrtf(s2[0] + 1e-6f), ki = rsqrtf(s2[1] + 1e-6f);
  float bet = beta[row];
  float4 qn4, kn4, vb4, kb4;
  qn4.x = q4.x * qi; qn4.y = q4.y * qi; qn4.z = q4.z * qi; qn4.w = q4.w * qi;
  kn4.x = k4.x * ki; kn4.y = k4.y * ki; kn4.z = k4.z * ki; kn4.w = k4.w * ki;
  vb4.x = v4.x * bet; vb4.y = v4.y * bet; vb4.z = v4.z * bet; vb4.w = v4.w * bet;
  kb4.x = kn4.x * bet; kb4.y = kn4.y * bet; kb4.z = kn4.z * bet; kb4.w = kn4.w * bet;
  *(float4*)(qn + base) = qn4;
  *(float4*)(kn + base) = kn4;
  *(float4*)(vb + base) = vb4;
  *(float4*)(kb + base) = kb4;
  int b = row >> 12, l = (row >> 2) & 1023, h = row & 3;
  uint2 o;
  o.x = cvt_pk_bf16(qn4.x, qn4.y);
  o.y = cvt_pk_bf16(qn4.z, qn4.w);
  *(uint2*)(qnbf + ((i64)(b * 4 + h) * 1024 + l) * 256 + lane * 4) = o;
}

// ---------------- FIR body ----------------
__device__ void fir2_body(
    int blk, const float* __restrict__ v,
    const float* __restrict__ f_s, const float* __restrict__ f_l,
    float* __restrict__ fs, float* __restrict__ fl, u16t* __restrict__ brcat) {
  int t = threadIdx.x;
  int b = blk >> 8, h = (blk >> 6) & 3, lc = blk & 63;
  int l0 = lc * 16;
  float flw[31], fsw[3];
  const float* flp = f_l + ((i64)h * 256 + t) * 31;
#pragma unroll
  for (int j = 0; j < 31; j++) flw[j] = flp[j];
  const float* fsp = f_s + ((i64)h * 256 + t) * 3;
#pragma unroll
  for (int j = 0; j < 3; j++) fsw[j] = fsp[j];
  float win[46];
#pragma unroll
  for (int r = 0; r < 46; r++) {
    int l = l0 - 30 + r;
    win[r] = (l >= 0) ? v[(((i64)b * 1024 + l) * 4 + h) * 256 + t] : 0.0f;
  }
#pragma unroll
  for (int i = 0; i < 16; i++) {
    float al = 0.0f;
#pragma unroll
    for (int j = 0; j < 31; j++) al += flw[j] * win[i + j];
    float as = fsw[0] * win[i + 28] + fsw[1] * win[i + 29] + fsw[2] * win[i + 30];
    i64 row = ((i64)b * 1024 + (l0 + i)) * 4 + h;
    fs[row * 256 + t] = as;
    fl[row * 256 + t] = al;
    brcat[row * 1024 + t] = f2bf(as);
    brcat[row * 1024 + 256 + t] = f2bf(al);
  }
}

// ---------------- phaseA3: phaseA(256) + transposes(2048) + wsum(24) + FIR(512) ----
// FIR moved here (deps: only vbuf from conv) — covers phaseA's serial
// UT-recurrence; frees mega6 blocks for branchW GEMM in the scan's shadow.
__global__ __launch_bounds__(256) void phaseA3_kernel(
    const float* __restrict__ qn, const float* __restrict__ kn,
    const float* __restrict__ vb, const float* __restrict__ kb,
    float* __restrict__ u_g, u16t* __restrict__ w_bf, u16t* __restrict__ attn_bf,
    u16t* __restrict__ knT,
    const float* __restrict__ gW1, const float* __restrict__ Wo,
    u16t* __restrict__ W1hT, u16t* __restrict__ W1bT, u16t* __restrict__ WoT,
    float* __restrict__ wsum,
    const float* __restrict__ vbuf, const float* __restrict__ firs,
    const float* __restrict__ firl, float* __restrict__ fs, float* __restrict__ fl,
    u16t* __restrict__ brcat) {
  __shared__ __attribute__((aligned(16))) char smem[37376];
  int blk = blockIdx.x, t = threadIdx.x;
  if (blk < 256) {
    float (*KN)[260] = (float(*)[260])smem;          // 33280 B
    float (*Ms)[32] = (float(*)[32])(smem + 33280);  // 4096 B
    int i = blk & 31, bh = blk >> 5;
    int rbase = ((bh >> 2) * LL + i * 32) * NH + (bh & 3);
    i64 bhn = blk;
#pragma unroll
    for (int ii = 0; ii < 8; ii++) {
      int fid = t + ii * 256;
      int c = fid >> 6, dq = (fid & 63) << 2;
      *(float4*)&KN[c][dq] = *(const float4*)(kn + (i64)(rbase + c * NH) * 256 + dq);
    }
    __syncthreads();
    int c = t >> 3, e0 = (t & 7) * 4;
    const float* kbp = kb + (i64)(rbase + c * NH) * 256;
    const float* qp = qn + (i64)(rbase + c * NH) * 256;
    float am[4] = {0, 0, 0, 0}, aa[4] = {0, 0, 0, 0};
    for (int d = 0; d < 256; d += 4) {
      float4 kv = *(const float4*)(kbp + d);
      float4 qv = *(const float4*)(qp + d);
#pragma unroll
      for (int z = 0; z < 4; z++) {
        float4 nv = *(const float4*)&KN[e0 + z][d];
        am[z] += kv.x * nv.x + kv.y * nv.y + kv.z * nv.z + kv.w * nv.w;
        aa[z] += qv.x * nv.x + qv.y * nv.y + qv.z * nv.z + qv.w * nv.w;
      }
    }
    {
      uint2 o;
      u16t a0 = (e0 + 0 <= c) ? f2bf(aa[0]) : 0;
      u16t a1 = (e0 + 1 <= c) ? f2bf(aa[1]) : 0;
      u16t a2 = (e0 + 2 <= c) ? f2bf(aa[2]) : 0;
      u16t a3 = (e0 + 3 <= c) ? f2bf(aa[3]) : 0;
      o.x = pk2(a0, a1); o.y = pk2(a2, a3);
      *(uint2*)(attn_bf + bhn * 1024 + c * 32 + e0) = o;
    }
#pragma unroll
    for (int z = 0; z < 4; z++) {
      int e = e0 + z;
      Ms[c][e] = (e < c) ? am[z] : 0.0f;
    }
    __syncthreads();
    float uc[32], wc[32];
#pragma unroll
    for (int cc = 0; cc < 32; cc++) {
      float uval = vb[(i64)(rbase + cc * NH) * 256 + t];
      float wval = kb[(i64)(rbase + cc * NH) * 256 + t];
#pragma unroll
      for (int c2 = 0; c2 < cc; c2++) {
        float m = Ms[cc][c2];
        uval -= m * uc[c2];
        wval -= m * wc[c2];
      }
      uc[cc] = uval; wc[cc] = wval;
      u_g[(bhn * 32 + cc) * 256 + t] = uval;
      w_bf[(bhn * 32 + cc) * 256 + t] = f2bf(-wval);
    }
    int d = t;
    u16t o[32];
#pragma unroll
    for (int cc = 0; cc < 32; cc++) o[cc] = f2bf(KN[cc][d]);
#pragma unroll
    for (int z = 0; z < 4; z++) {
      uint4 vv;
      vv.x = pk2(o[z * 8 + 0], o[z * 8 + 1]);
      vv.y = pk2(o[z * 8 + 2], o[z * 8 + 3]);
      vv.z = pk2(o[z * 8 + 4], o[z * 8 + 5]);
      vv.w = pk2(o[z * 8 + 6], o[z * 8 + 7]);
      *(uint4*)(knT + (bhn * 256 + d) * 32 + z * 8) = vv;
    }
  } else if (blk < 2304) {
    float (*tile)[33] = (float(*)[33])smem;
    int pb = blk - 256;
    if (pb < 1024) {
      int which = pb >> 9, bi = pb & 511;
      const float* in = gW1 + (which ? (i64)4096 * 512 : 0);
      transcast_body(in, 512, which ? W1bT : W1hT, 1024, bi & 15, bi >> 4, tile);
    } else {
      int bi = pb - 1024;
      transcast_body(Wo, 1024, WoT, 1024, bi & 31, bi >> 5, tile);
    }
  } else if (blk < 2328) {
    int bi = blk - 2304;         // 24 blocks: 12 stats x 2 col-halves
    int s12 = bi >> 1, col = (bi & 1) * 256 + t;
    const float* p = gW1 + (i64)(1024 + s12 * 256) * 512 + col;
    float acc = 0.0f;
    for (int r = 0; r < 256; r++) acc += p[(i64)r * 512];
    wsum[s12 * 512 + col] = acc;
  } else {
    fir2_body(blk - 2328, vbuf, firs, firl, fs, fl, brcat);
  }
}

// ---------------- delta scan body (verbatim passing version) ----------------
#define SROW 264
struct ScanBuf {
  short8 m8[8];
  f32x4 uc4;
  short8 af;
  short8 kf[4];
};

__device__ void delta_scan_body(
    int blk,
    const u16t* __restrict__ wbf, const u16t* __restrict__ knT,
    const float* __restrict__ u_g, const u16t* __restrict__ qnbf,
    const u16t* __restrict__ attnbf,
    float* __restrict__ dlt, u16t* __restrict__ brcat,
    u16t* Sbf, u16t* Ubf) {
  int t = threadIdx.x, w = t >> 6, lane = t & 63;
  int l15 = lane & 15, quad = lane >> 4;
  int bh = blk & 7, jb = blk >> 3, j0 = jb * 16;
  int b_ = bh >> 2, h_ = bh & 3;
  bool isU = (w < 2);
  int wc = isU ? w : (w - 2);
  for (int idx = t; idx < 16 * SROW; idx += 256) Sbf[idx] = 0;
  f32x4 accS[4] = {};
  __syncthreads();
  __builtin_amdgcn_s_setprio(1);

  auto load_chunk = [&](int i, ScanBuf& B) {
    i64 bhn = (i64)bh * 32 + i;
    const u16t* mbase = isU
        ? wbf + (bhn * 32 + wc * 16 + l15) * 256 + quad * 8
        : qnbf + ((i64)bh * 1024 + i * 32 + wc * 16 + l15) * 256 + quad * 8;
#pragma unroll
    for (int kd = 0; kd < 8; kd++) B.m8[kd] = *(const short8*)(mbase + kd * 32);
    if (isU) {
      int cm = wc * 16 + quad * 4;
#pragma unroll
      for (int r = 0; r < 4; r++)
        B.uc4[r] = u_g[(bhn * 32 + cm + r) * 256 + j0 + l15];
    } else {
      B.af = *(const short8*)(attnbf + bhn * 1024 + (wc * 16 + l15) * 32 + quad * 8);
    }
#pragma unroll
    for (int dt = 0; dt < 4; dt++)
      B.kf[dt] = *(const short8*)(knT + (bhn * 256 + w * 64 + dt * 16 + l15) * 32 + quad * 8);
  };

  auto process = [&](int i, ScanBuf& B) {
    f32x4 zero = {};
    f32x4 ca = isU ? B.uc4 : zero;
    f32x4 cb = zero;
#pragma unroll
    for (int kd = 0; kd < 4; kd++) {
      short8 sfa = *(const short8*)&Sbf[l15 * SROW + kd * 32 + quad * 8];
      short8 sfb = *(const short8*)&Sbf[l15 * SROW + (kd + 4) * 32 + quad * 8];
      ca = MFMA_BF16(B.m8[kd], sfa, ca);
      cb = MFMA_BF16(B.m8[kd + 4], sfb, cb);
    }
    f32x4 cacc;
#pragma unroll
    for (int r = 0; r < 4; r++) cacc[r] = ca[r] + cb[r];
    if (isU) {
      int cm = wc * 16 + quad * 4;
      uint2 o;
      o.x = cvt_pk_bf16(cacc[0], cacc[1]);
      o.y = cvt_pk_bf16(cacc[2], cacc[3]);
      *(uint2*)&Ubf[l15 * 40 + cm] = o;
    }
    barrier_lds_only();
    short8 bu = *(const short8*)&Ubf[l15 * 40 + quad * 8];
    if (!isU) {
      cacc = MFMA_BF16(B.af, bu, cacc);
#pragma unroll
      for (int rg = 0; rg < 4; rg++) {
        int l = i * 32 + wc * 16 + quad * 4 + rg;
        i64 row = ((i64)b_ * 1024 + l) * 4 + h_;
        dlt[row * 256 + j0 + l15] = cacc[rg];
        brcat[row * 1024 + 512 + j0 + l15] = f2bf(cacc[rg]);
      }
    }
#pragma unroll
    for (int dt = 0; dt < 4; dt++) accS[dt] = MFMA_BF16(B.kf[dt], bu, accS[dt]);
#pragma unroll
    for (int dt = 0; dt < 4; dt++) {
      uint2 o;
      o.x = cvt_pk_bf16(accS[dt][0], accS[dt][1]);
      o.y = cvt_pk_bf16(accS[dt][2], accS[dt][3]);
      *(uint2*)&Sbf[l15 * SROW + w * 64 + dt * 16 + quad * 4] = o;
    }
    barrier_lds_only();
  };

  ScanBuf b0, b1;
  load_chunk(0, b0);
#pragma unroll 1
  for (int ii = 0; ii < 16; ii++) {
    int i = ii * 2;
    load_chunk(i + 1, b1);
    process(i, b0);
    if (ii < 15) load_chunk(i + 2, b0);
    process(i + 1, b1);
  }
  __builtin_amdgcn_s_setprio(0);
}

// ---------------- mega6: scan(128) + hbase gemm(64) + branchW partial(256) ----
// branchW partial sums K in {768..1023} (v cols, from conv) and {0..511}
// (fs/fl cols, from FIR in phaseA3) — NEVER touches cols 512-767 which the
// scan blocks write concurrently. The dlt K-block is added by branchw_dlt.
__global__ __launch_bounds__(256) void mega6_kernel(
    const u16t* __restrict__ wbf, const u16t* __restrict__ knT,
    const float* __restrict__ u_g, const u16t* __restrict__ qnbf,
    const u16t* __restrict__ attnbf, float* __restrict__ dlt, u16t* __restrict__ brcat,
    const u16t* __restrict__ xbf, const u16t* __restrict__ W1hT,
    float* __restrict__ hbase,
    const u16t* __restrict__ W1bT, float* __restrict__ branchW) {
  __shared__ __attribute__((aligned(16))) char smem[32768];
  int blk = blockIdx.x;
  if (blk < 128) {
    u16t* Sbf = (u16t*)smem;
    u16t* Ubf = Sbf + 16 * SROW;
    delta_scan_body(blk, wbf, knT, u_g, qnbf, attnbf, dlt, brcat, Sbf, Ubf);
  } else if (blk < 192) {
    int bi = blk - 128;
    u16t* As = (u16t*)smem;
    u16t* Bs = As + 2 * 128 * 32;
    gemm_bt_body(xbf, W1hT, hbase, 1024, 512, (bi & 3) * 128, (bi >> 2) * 128, As, Bs);
  } else {
    int bi = blk - 192;
    u16t* As = (u16t*)smem;
    u16t* Bs = As + 2 * 128 * 32;
    int n0 = (bi & 3) * 128, m0 = (bi >> 2) * 128;
    f32x4 acc[4][4] = {};
    gemm_tiles_acc(brcat, W1bT, 1024, 768, 256, n0, m0, As, Bs, acc);
    gemm_tiles_acc(brcat, W1bT, 1024, 0, 512, n0, m0, As, Bs, acc);
    gemm_store(branchW, 512, n0, m0, acc, false);
  }
}

// ---------------- branchw_dlt: += brcat[:,512:768] @ W1bT[:,512:768]^T ----------------
__global__ __launch_bounds__(256) void branchw_dlt_kernel(
    const u16t* __restrict__ brcat, const u16t* __restrict__ W1bT,
    float* __restrict__ branchW) {
  __shared__ u16t As[2 * 128 * 32];
  __shared__ u16t Bs[2 * 128 * 32];
  int bi = blockIdx.x;
  int n0 = (bi & 3) * 128, m0 = (bi >> 2) * 128;
  f32x4 acc[4][4] = {};
  gemm_tiles_acc(brcat, W1bT, 1024, 512, 256, n0, m0, As, Bs, acc);
  gemm_store(branchW, 512, n0, m0, acc, true);
}

// ---------------- gate MLP tail + mix + RMS norm: WAVE-PER-ROW ----------------
__global__ __launch_bounds__(256) void gatemix_kernel(
    const float* __restrict__ hbase, const float* __restrict__ brW,
    const float* __restrict__ wsum,
    const float* __restrict__ gb1, const float* __restrict__ gW2,
    const float* __restrict__ gb2, const float* __restrict__ temp,
    const float* __restrict__ epsf,
    const float* __restrict__ fs, const float* __restrict__ fl,
    const float* __restrict__ dlt, const float* __restrict__ v,
    const float* __restrict__ onw, u16t* __restrict__ out) {
  int t = threadIdx.x, lane = t & 63, wv = t >> 6;
  int row = blockIdx.x * 4 + wv;      // (b*1024+l)*4+h
  int bl = row >> 2, h = row & 3;
  i64 base = (i64)row * 256 + lane * 4;
  float4 vfs = *(const float4*)(fs + base);
  float4 vfl = *(const float4*)(fl + base);
  float4 vdl = *(const float4*)(dlt + base);
  float4 vvv = *(const float4*)(v + base);
  float r8[8];
  r8[0] = vfs.x + vfs.y + vfs.z + vfs.w;
  r8[1] = vfs.x * vfs.x + vfs.y * vfs.y + vfs.z * vfs.z + vfs.w * vfs.w;
  r8[2] = vfl.x + vfl.y + vfl.z + vfl.w;
  r8[3] = vfl.x * vfl.x + vfl.y * vfl.y + vfl.z * vfl.z + vfl.w * vfl.w;
  r8[4] = vdl.x + vdl.y + vdl.z + vdl.w;
  r8[5] = vdl.x * vdl.x + vdl.y * vdl.y + vdl.z * vdl.z + vdl.w * vdl.w;
  r8[6] = vvv.x + vvv.y + vvv.z + vvv.w;
  r8[7] = vvv.x * vvv.x + vvv.y * vvv.y + vvv.z * vvv.z + vvv.w * vvv.w;
#pragma unroll
  for (int off = 1; off < 64; off <<= 1) {
#pragma unroll
    for (int i = 0; i < 8; i++) r8[i] += __shfl_xor(r8[i], off);
  }
  float m4[4];
  m4[0] = fmaxf(fmaxf(vfs.x, vfs.y), fmaxf(vfs.z, vfs.w));
  m4[1] = fmaxf(fmaxf(vfl.x, vfl.y), fmaxf(vfl.z, vfl.w));
  m4[2] = fmaxf(fmaxf(vdl.x, vdl.y), fmaxf(vdl.z, vdl.w));
  m4[3] = fmaxf(fmaxf(vvv.x, vvv.y), fmaxf(vvv.z, vvv.w));
#pragma unroll
  for (int off = 1; off < 64; off <<= 1) {
#pragma unroll
    for (int i = 0; i < 4; i++) m4[i] = fmaxf(m4[i], __shfl_xor(m4[i], off));
  }
  float st[12];
#pragma unroll
  for (int p = 0; p < 4; p++) {
    st[p * 3 + 0] = r8[p * 2] * (1.0f / 256.0f);
    st[p * 3 + 1] = sqrtf(fmaxf(r8[p * 2 + 1] * (1.0f / 256.0f), 1e-8f));
    st[p * 3 + 2] = m4[p];
  }
  float lg[4] = {0, 0, 0, 0};
#pragma unroll
  for (int jj = 0; jj < 8; jj++) {
    int o = jj * 64 + lane;
    float hm = hbase[(i64)bl * 512 + o] + brW[(i64)row * 512 + o] + gb1[o];
#pragma unroll
    for (int s = 0; s < 12; s++) hm += st[s] * wsum[s * 512 + o];
    float ge = 0.5f * hm * (1.0f + erff(hm * 0.70710678118654752f));
    float4 w2 = *(const float4*)(gW2 + o * 4);
    lg[0] += ge * w2.x; lg[1] += ge * w2.y; lg[2] += ge * w2.z; lg[3] += ge * w2.w;
  }
#pragma unroll
  for (int off = 1; off < 64; off <<= 1) {
#pragma unroll
    for (int i = 0; i < 4; i++) lg[i] += __shfl_xor(lg[i], off);
  }
  float tt = fminf(fmaxf(temp[h], 0.2f), 10.0f);
  float l0 = (lg[0] + gb2[0]) / tt;
  float l1 = (lg[1] + gb2[1]) / tt;
  float l2 = (lg[2] + gb2[2]) / tt;
  float l3 = (lg[3] + gb2[3]) / tt;
  float m = fmaxf(fmaxf(l0, l1), fmaxf(l2, l3));
  float e0 = expf(l0 - m), e1 = expf(l1 - m), e2 = expf(l2 - m), e3 = expf(l3 - m);
  float ssum = e0 + e1 + e2 + e3;
  float w0 = e0 / ssum, w1 = e1 / ssum, w2 = e2 / ssum, w3 = e3 / ssum;
  w0 = fmaxf(w0, fminf(fmaxf(epsf[h * 4 + 0], 1e-7f), 0.1f));
  w1 = fmaxf(w1, fminf(fmaxf(epsf[h * 4 + 1], 1e-7f), 0.1f));
  w2 = fmaxf(w2, fminf(fmaxf(epsf[h * 4 + 2], 1e-7f), 0.1f));
  w3 = fmaxf(w3, fminf(fmaxf(epsf[h * 4 + 3], 1e-7f), 0.1f));
  float s2 = w0 + w1 + w2 + w3;
  float g0 = w0 / s2, g1 = w1 / s2, g2 = w2 / s2, g3 = w3 / s2;
  float4 o4;
  o4.x = g0 * vfs.x + g1 * vfl.x + g2 * vdl.x + g3 * vvv.x;
  o4.y = g0 * vfs.y + g1 * vfl.y + g2 * vdl.y + g3 * vvv.y;
  o4.z = g0 * vfs.z + g1 * vfl.z + g2 * vdl.z + g3 * vvv.z;
  o4.w = g0 * vfs.w + g1 * vfl.w + g2 * vdl.w + g3 * vvv.w;
  float ss = o4.x * o4.x + o4.y * o4.y + o4.z * o4.z + o4.w * o4.w;
#pragma unroll
  for (int off = 1; off < 64; off <<= 1) ss += __shfl_xor(ss, off);
  float scale = rsqrtf(ss * (1.0f / 256.0f) + 1e-5f);
  float4 ow4 = *(const float4*)(onw + lane * 4);
  uint2 ow;
  ow.x = cvt_pk_bf16(o4.x * scale * ow4.x, o4.y * scale * ow4.y);
  ow.y = cvt_pk_bf16(o4.z * scale * ow4.z, o4.w * scale * ow4.w);
  *(uint2*)(out + (i64)bl * 1024 + h * 256 + lane * 4) = ow;
}

extern "C" void kernel_launch(void* const* d_in, const int* in_sizes, int n_in,
                              void* d_out, int out_size, void* d_ws, size_t ws_size,
                              hipStream_t stream) {
  (void)in_sizes; (void)n_in; (void)out_size; (void)ws_size;
  const float* x    = (const float*)d_in[0];
  const float* Wq   = (const float*)d_in[1];
  const float* Wk   = (const float*)d_in[2];
  const float* Wv   = (const float*)d_in[3];
  const float* Wb   = (const float*)d_in[4];
  const float* qcw  = (const float*)d_in[5];
  const float* kcw  = (const float*)d_in[6];
  const float* vcw  = (const float*)d_in[7];
  const float* gW1  = (const float*)d_in[8];
  const float* gb1  = (const float*)d_in[9];
  const float* gW2  = (const float*)d_in[10];
  const float* gb2  = (const float*)d_in[11];
  const float* temp = (const float*)d_in[12];
  const float* epsf = (const float*)d_in[13];
  const float* onw  = (const float*)d_in[14];
  const float* Wo   = (const float*)d_in[15];
  const float* firs = (const float*)d_in[16];
  const float* firl = (const float*)d_in[17];
  float* out = (float*)d_out;

  float* ws = (float*)d_ws;
  // ---- workspace map (float offsets) ----
  float* qkv_pre  = ws + 0;                       // 2048*3072 fp32 (dead after conv)
  float* branchW  = ws + 0;                       // 8192*512 fp32 (step 6+)
  float* hbase    = ws + 4194304;                 // 2048*512 fp32 (step 6+)
  u16t*  W1hT     = (u16t*)(ws + 5242880);        // 512x1024 bf16 (step 5+)
  u16t*  W1bT     = (u16t*)(ws + 5505024);        // 512x1024 bf16
  u16t*  WoT      = (u16t*)(ws + 5767168);        // 1024x1024 bf16
  u16t*  brcat    = (u16t*)(ws + 6291456);        // 8192*1024 bf16
  float* qbuf     = ws + 10485760; float* qn = qbuf;
  float* kbuf     = ws + 12582912; float* kn = kbuf;
  float* vbuf     = ws + 14680064;
  float* vb       = ws + 16777216;                // dead after phaseA3
  u16t*  omix_bf  = (u16t*)(ws + 16777216);       // gatemix+ (2048*1024 bf16)
  float* kb       = ws + 18874368;                // dead after phaseA3
  float* dlt      = ws + 18874368;                // scan output
  float* u_g      = ws + 20971520;
  u16t*  w_bf     = (u16t*)(ws + 23068672);
  u16t*  qn_bf    = (u16t*)(ws + 24117248);
  u16t*  knT      = (u16t*)(ws + 25165824);
  u16t*  attn_bf  = (u16t*)(ws + 26214400);
  float* fs       = ws + 26345472;
  float* fl       = ws + 28442624;
  u16t*  xbf      = (u16t*)(ws + 30539776);
  u16t*  WqkvT    = (u16t*)(ws + 31588352);
  float* betab    = ws + 33161216;                // 8192 fp32
  float* wsum     = ws + 33267712;

  // 1) prep: QKV weight transpose + x cast + beta
  prep_kernel<<<7168, 256, 0, stream>>>(Wq, Wk, Wv, x, Wb, WqkvT, xbf, betab);
  // 2) QKV GEMM (2-phase dbuf global_load_lds staging)
  gemm_bt_kernel<<<dim3(24, 16), 256, 0, stream>>>(xbf, WqkvT, qkv_pre, 1024, 3072);
  // 3) conv+silu vectorized x4 (v also -> brcat col 768); kills qkv_pre
  conv_silu3_kernel<<<6144, 256, 0, stream>>>(qkv_pre, qcw, kcw, vcw, qbuf, kbuf, vbuf, brcat);
  // 4) preprocess (wave-per-row, float4)
  preprocess_kernel<<<2048, 256, 0, stream>>>(qbuf, kbuf, vbuf, betab, qn, kn, vb, kb, qn_bf);
  // 5) phaseA3: UT-transform + W1/Wo transposes + wsum + FIR
  phaseA3_kernel<<<2840, 256, 0, stream>>>(qn, kn, vb, kb, u_g, w_bf, attn_bf, knT,
                                           gW1, Wo, W1hT, W1bT, WoT, wsum,
                                           vbuf, firs, firl, fs, fl, brcat);
  // 6) mega6: scan + hbase GEMM + branchW partial (K 768-1024 and 0-512)
  mega6_kernel<<<448, 256, 0, stream>>>(w_bf, knT, u_g, qn_bf, attn_bf, dlt, brcat,
                                        xbf, W1hT, hbase, W1bT, branchW);
  // 7) branchW dlt K-block (512-768), accumulate
  branchw_dlt_kernel<<<256, 256, 0, stream>>>(brcat, W1bT, branchW);
  // 8) gate tail + mix + RMS (wave-per-row, no barriers)
  gatemix_kernel<<<2048, 256, 0, stream>>>(hbase, branchW, wsum, gb1, gW2, gb2,
                                           temp, epsf, fs, fl, dlt, vbuf, onw, omix_bf);
  // 9) final projection
  gemm_bt_kernel<<<dim3(8, 16), 256, 0, stream>>>(omix_bf, WoT, out, 1024, 1024);
}

// Round 13
// 303.311 us; speedup vs baseline: 1.1301x; 1.0350x over previous
//
#include <hip/hip_runtime.h>
#include <math.h>

// Problem constants
#define BB 2
#define LL 1024
#define HIDD 1024
#define NH 4
#define DD 256
#define NCH 32
#define ROWS 2048
#define HROWS 8192

typedef long long i64;
typedef unsigned short u16t;
typedef unsigned int u32t;
typedef __attribute__((ext_vector_type(8))) short short8;
typedef __attribute__((ext_vector_type(4))) float f32x4;
#define MFMA_BF16(a, b, c) __builtin_amdgcn_mfma_f32_16x16x32_bf16(a, b, c, 0, 0, 0)

__device__ __forceinline__ float sigmoidf_(float x) { return 1.0f / (1.0f + expf(-x)); }

__device__ __forceinline__ u16t f2bf(float f) {
  u32t u = __float_as_uint(f);
  u = u + 0x7FFFu + ((u >> 16) & 1u);
  return (u16t)(u >> 16);
}
__device__ __forceinline__ u32t pk2(u16t a, u16t b) { return (u32t)a | ((u32t)b << 16); }

// HW packed f32->bf16 RNE convert (gfx950): 1 instr vs 6-op bit-trick pair.
__device__ __forceinline__ u32t cvt_pk_bf16(float lo, float hi) {
  u32t r;
  asm("v_cvt_pk_bf16_f32 %0, %1, %2" : "=v"(r) : "v"(lo), "v"(hi));
  return r;
}

// async global->LDS, 16B per lane (wave-uniform LDS base, per-lane global src).
__device__ __forceinline__ void async_load16(const u16t* g, u16t* l) {
  __builtin_amdgcn_global_load_lds(
      (const __attribute__((address_space(1))) u32t*)g,
      (__attribute__((address_space(3))) u32t*)l, 16, 0, 0);
}

// counted-wait barrier: drain only LDS ops, keep global loads in flight.
__device__ __forceinline__ void barrier_lds_only() {
  asm volatile("s_waitcnt lgkmcnt(0)" ::: "memory");
  __builtin_amdgcn_s_barrier();
  asm volatile("" ::: "memory");
}

// ---------------- block reduction helper (blockDim == 256) ----------------
template<int N>
__device__ __forceinline__ void block_reduce_sum(float* v, float* scratch) {
  int lane = threadIdx.x & 63, wid = threadIdx.x >> 6;
#pragma unroll
  for (int i = 0; i < N; i++) {
    float x = v[i];
#pragma unroll
    for (int off = 1; off < 64; off <<= 1) x += __shfl_xor(x, off);
    if (lane == 0) scratch[wid * N + i] = x;
  }
  __syncthreads();
#pragma unroll
  for (int i = 0; i < N; i++)
    v[i] = scratch[i] + scratch[N + i] + scratch[2 * N + i] + scratch[3 * N + i];
  __syncthreads();
}

// ---------------- transpose+cast body: fp32 [K][N] -> bf16 [N][K], one 32x32 tile ----------------
__device__ __forceinline__ void transcast_body(
    const float* __restrict__ in, int ldin, u16t* __restrict__ out, int ldout,
    int nbi, int kbi, float (*tile)[33]) {
  int tx = threadIdx.x & 31, ty = threadIdx.x >> 5;
  int nb = nbi * 32, kb = kbi * 32;
#pragma unroll
  for (int r = 0; r < 4; r++)
    tile[ty + r * 8][tx] = in[(i64)(kb + ty + r * 8) * ldin + nb + tx];
  __syncthreads();
#pragma unroll
  for (int r = 0; r < 4; r++)
    out[(i64)(nb + ty + r * 8) * ldout + kb + tx] = f2bf(tile[tx][ty + r * 8]);
}

// ---------------- prep (step 1): WqkvT(3072) + xbf(2048) + beta(2048) ----------------
__global__ __launch_bounds__(256) void prep_kernel(
    const float* __restrict__ Wq, const float* __restrict__ Wk, const float* __restrict__ Wv,
    const float* __restrict__ x, const float* __restrict__ Wb,
    u16t* __restrict__ WqkvT, u16t* __restrict__ xbf, float* __restrict__ betab) {
  __shared__ float tile[32][33];
  int blk = blockIdx.x, t = threadIdx.x;
  if (blk < 3072) {
    int m = blk >> 10, bi = blk & 1023;
    const float* in = m == 0 ? Wq : m == 1 ? Wk : Wv;
    transcast_body(in, 1024, WqkvT + (i64)m * 1024 * 1024, 1024, bi & 31, bi >> 5, tile);
  } else if (blk < 5120) {
    i64 e = ((i64)(blk - 3072) * 256 + t) * 4;
    float4 v = *(const float4*)(x + e);
    uint2 o;
    o.x = pk2(f2bf(v.x), f2bf(v.y));
    o.y = pk2(f2bf(v.z), f2bf(v.w));
    *(uint2*)(xbf + e) = o;
  } else {
    int row = blk - 5120;
    float a[4] = {0, 0, 0, 0};
    for (int c = t; c < 1024; c += 256) {
      float xv = x[(i64)row * 1024 + c];
      float4 wv = *(const float4*)(Wb + c * 4);
      a[0] += xv * wv.x; a[1] += xv * wv.y; a[2] += xv * wv.z; a[3] += xv * wv.w;
    }
    block_reduce_sum<4>(a, (float*)tile);
    if (t == 0) {
#pragma unroll
      for (int g = 0; g < 4; g++) betab[row * 4 + g] = sigmoidf_(a[g]);
    }
  }
}

// ---------------- K-range accumulating GEMM tiles (2-phase dbuf, async LDS) ----
__device__ __forceinline__ void gemm_tiles_acc(
    const u16t* __restrict__ A, const u16t* __restrict__ B,
    i64 ld, int koff, int Kext, int n0, int m0,
    u16t* As, u16t* Bs, f32x4 (&acc)[4][4]) {
  int t = threadIdx.x;
  int w = t >> 6, lane = t & 63;
  int l15 = lane & 15, quad = lane >> 4;
  int wm = (w & 1) * 64, wn = (w >> 1) * 64;
  int c0 = 2 * w, c1 = 2 * w + 1;
  int srow0 = c0 * 16 + (lane >> 2);
  int srow1 = c1 * 16 + (lane >> 2);
  int scol = (lane & 3) * 8;
  const u16t* Ag0 = A + (i64)(m0 + srow0) * ld + koff + scol;
  const u16t* Ag1 = A + (i64)(m0 + srow1) * ld + koff + scol;
  const u16t* Bg0 = B + (i64)(n0 + srow0) * ld + koff + scol;
  const u16t* Bg1 = B + (i64)(n0 + srow1) * ld + koff + scol;
  int lb0 = c0 * 512, lb1 = c1 * 512;   // wave-uniform LDS chunk bases
  async_load16(Ag0, As + lb0);
  async_load16(Ag1, As + lb1);
  async_load16(Bg0, Bs + lb0);
  async_load16(Bg1, Bs + lb1);
  __syncthreads();
  int nt = Kext >> 5;
  for (int ti = 0; ti < nt; ++ti) {
    int cur = (ti & 1) << 12;           // buffer offset (4096 u16)
    if (ti + 1 < nt) {
      int nxt = ((ti + 1) & 1) << 12;
      int k = (ti + 1) << 5;
      async_load16(Ag0 + k, As + nxt + lb0);
      async_load16(Ag1 + k, As + nxt + lb1);
      async_load16(Bg0 + k, Bs + nxt + lb0);
      async_load16(Bg1 + k, Bs + nxt + lb1);
    }
    short8 a[4], b[4];
#pragma unroll
    for (int mt = 0; mt < 4; mt++)
      a[mt] = *(const short8*)&As[cur + (wm + mt * 16 + l15) * 32 + quad * 8];
#pragma unroll
    for (int ntt = 0; ntt < 4; ntt++)
      b[ntt] = *(const short8*)&Bs[cur + (wn + ntt * 16 + l15) * 32 + quad * 8];
#pragma unroll
    for (int mt = 0; mt < 4; mt++)
#pragma unroll
      for (int ntt = 0; ntt < 4; ntt++)
        acc[mt][ntt] = MFMA_BF16(a[mt], b[ntt], acc[mt][ntt]);
    __syncthreads();   // drains vmcnt(0): prefetched tile becomes visible
  }
}

__device__ __forceinline__ void gemm_store(
    float* __restrict__ C, int ldc, int n0, int m0, f32x4 (&acc)[4][4], bool add) {
  int t = threadIdx.x;
  int w = t >> 6, lane = t & 63;
  int l15 = lane & 15, quad = lane >> 4;
  int wm = (w & 1) * 64, wn = (w >> 1) * 64;
#pragma unroll
  for (int mt = 0; mt < 4; mt++) {
    int r0 = m0 + wm + mt * 16 + quad * 4;
#pragma unroll
    for (int nt = 0; nt < 4; nt++) {
      int cc = n0 + wn + nt * 16 + l15;
#pragma unroll
      for (int rg = 0; rg < 4; rg++) {
        i64 idx = (i64)(r0 + rg) * ldc + cc;
        C[idx] = add ? (C[idx] + acc[mt][nt][rg]) : acc[mt][nt][rg];
      }
    }
  }
}

__device__ __forceinline__ void gemm_bt_body(
    const u16t* __restrict__ A, const u16t* __restrict__ B,
    float* __restrict__ C, int K, int ldc, int n0, int m0,
    u16t* As, u16t* Bs) {
  f32x4 acc[4][4] = {};
  gemm_tiles_acc(A, B, K, 0, K, n0, m0, As, Bs, acc);
  gemm_store(C, ldc, n0, m0, acc, false);
}

__global__ __launch_bounds__(256) void gemm_bt_kernel(
    const u16t* __restrict__ A, const u16t* __restrict__ B,
    float* __restrict__ C, int K, int ldc) {
  __shared__ u16t As[2 * 128 * 32];
  __shared__ u16t Bs[2 * 128 * 32];
  gemm_bt_body(A, B, C, K, ldc, blockIdx.x * 128, blockIdx.y * 128, As, Bs);
}

// ---------------- conv+silu FUSED with preprocess (l2norm/beta-scale) ----------------
// Block = (seg, row); thread t covers channels 4t..4t+3, so head h = t>>6 ==
// wave id: the per-head sumsq reduce is a pure 64-lane butterfly (same tree
// shape as the old preprocess — FP-identical). beta ready from prep (step 1).
// seg0 -> qn + qn_bf; seg1 -> kn + kb; seg2 -> vbuf + vb + brcat col 768.
// Old preprocess dispatch and the q/k fp32 round-trip are deleted.
__global__ __launch_bounds__(256) void conv_fused_kernel(
    const float* __restrict__ pre, const float* __restrict__ qw,
    const float* __restrict__ kw, const float* __restrict__ vw,
    const float* __restrict__ betab,
    float* __restrict__ qn, float* __restrict__ kn,
    float* __restrict__ vbuf, float* __restrict__ vb, float* __restrict__ kb,
    u16t* __restrict__ qnbf, u16t* __restrict__ brcat) {
  int seg = blockIdx.x >> 11;          // 3 segs x 2048 rows
  int row = blockIdx.x & 2047;         // b*1024 + l
  int l = row & 1023;
  int c = threadIdx.x * 4;
  const float* w = seg == 0 ? qw : seg == 1 ? kw : vw;
  float4 w0 = *(const float4*)(w + (i64)(c + 0) * 4);
  float4 w1 = *(const float4*)(w + (i64)(c + 1) * 4);
  float4 w2 = *(const float4*)(w + (i64)(c + 2) * 4);
  float4 w3 = *(const float4*)(w + (i64)(c + 3) * 4);
  const float* base = pre + (i64)row * 3072 + (seg << 10) + c;
  float4 x0 = *(const float4*)(base);
  float4 acc;
  acc.x = w0.w * x0.x; acc.y = w1.w * x0.y; acc.z = w2.w * x0.z; acc.w = w3.w * x0.w;
  if (l >= 1) {
    float4 xm = *(const float4*)(base - 3072);
    acc.x += w0.z * xm.x; acc.y += w1.z * xm.y; acc.z += w2.z * xm.z; acc.w += w3.z * xm.w;
  }
  if (l >= 2) {
    float4 xm = *(const float4*)(base - 2 * 3072);
    acc.x += w0.y * xm.x; acc.y += w1.y * xm.y; acc.z += w2.y * xm.z; acc.w += w3.y * xm.w;
  }
  if (l >= 3) {
    float4 xm = *(const float4*)(base - 3 * 3072);
    acc.x += w0.x * xm.x; acc.y += w1.x * xm.y; acc.z += w2.x * xm.z; acc.w += w3.x * xm.w;
  }
  float4 r;
  r.x = acc.x * sigmoidf_(acc.x);
  r.y = acc.y * sigmoidf_(acc.y);
  r.z = acc.z * sigmoidf_(acc.z);
  r.w = acc.w * sigmoidf_(acc.w);
  int h = threadIdx.x >> 6;            // head == wave id
  i64 obase = (i64)row * 1024 + c;     // == ((row*4+h)*256 + (c&255))
  if (seg == 0) {
    float ss = r.x * r.x + r.y * r.y + r.z * r.z + r.w * r.w;
#pragma unroll
    for (int off = 1; off < 64; off <<= 1) ss += __shfl_xor(ss, off);
    float qi = rsqrtf(ss + 1e-6f);
    float4 n4;
    n4.x = r.x * qi; n4.y = r.y * qi; n4.z = r.z * qi; n4.w = r.w * qi;
    *(float4*)(qn + obase) = n4;
    int b = row >> 10;
    uint2 o;
    o.x = cvt_pk_bf16(n4.x, n4.y);
    o.y = cvt_pk_bf16(n4.z, n4.w);
    *(uint2*)(qnbf + ((i64)(b * 4 + h) * 1024 + l) * 256 + (c & 255)) = o;
  } else if (seg == 1) {
    float ss = r.x * r.x + r.y * r.y + r.z * r.z + r.w * r.w;
#pragma unroll
    for (int off = 1; off < 64; off <<= 1) ss += __shfl_xor(ss, off);
    float ki = rsqrtf(ss + 1e-6f);
    float bet = betab[row * 4 + h];
    float4 n4, kb4;
    n4.x = r.x * ki; n4.y = r.y * ki; n4.z = r.z * ki; n4.w = r.w * ki;
    kb4.x = n4.x * bet; kb4.y = n4.y * bet; kb4.z = n4.z * bet; kb4.w = n4.w * bet;
    *(float4*)(kn + obase) = n4;
    *(float4*)(kb + obase) = kb4;
  } else {
    float bet = betab[row * 4 + h];
    float4 vb4;
    vb4.x = r.x * bet; vb4.y = r.y * bet; vb4.z = r.z * bet; vb4.w = r.w * bet;
    *(float4*)(vbuf + obase) = r;
    *(float4*)(vb + obase) = vb4;
    uint2 o;
    o.x = cvt_pk_bf16(r.x, r.y);
    o.y = cvt_pk_bf16(r.z, r.w);
    *(uint2*)(brcat + ((i64)row * 4 + (c >> 8)) * 1024 + 768 + (c & 255)) = o;
  }
}

// ---------------- FIR body ----------------
__device__ void fir2_body(
    int blk, const float* __restrict__ v,
    const float* __restrict__ f_s, const float* __restrict__ f_l,
    float* __restrict__ fs, float* __restrict__ fl, u16t* __restrict__ brcat) {
  int t = threadIdx.x;
  int b = blk >> 8, h = (blk >> 6) & 3, lc = blk & 63;
  int l0 = lc * 16;
  float flw[31], fsw[3];
  const float* flp = f_l + ((i64)h * 256 + t) * 31;
#pragma unroll
  for (int j = 0; j < 31; j++) flw[j] = flp[j];
  const float* fsp = f_s + ((i64)h * 256 + t) * 3;
#pragma unroll
  for (int j = 0; j < 3; j++) fsw[j] = fsp[j];
  float win[46];
#pragma unroll
  for (int r = 0; r < 46; r++) {
    int l = l0 - 30 + r;
    win[r] = (l >= 0) ? v[(((i64)b * 1024 + l) * 4 + h) * 256 + t] : 0.0f;
  }
#pragma unroll
  for (int i = 0; i < 16; i++) {
    float al = 0.0f;
#pragma unroll
    for (int j = 0; j < 31; j++) al += flw[j] * win[i + j];
    float as = fsw[0] * win[i + 28] + fsw[1] * win[i + 29] + fsw[2] * win[i + 30];
    i64 row = ((i64)b * 1024 + (l0 + i)) * 4 + h;
    fs[row * 256 + t] = as;
    fl[row * 256 + t] = al;
    brcat[row * 1024 + t] = f2bf(as);
    brcat[row * 1024 + 256 + t] = f2bf(al);
  }
}

// ---------------- phaseA3: phaseA(256) + transposes(2048) + wsum(24) + FIR(512) ----
__global__ __launch_bounds__(256) void phaseA3_kernel(
    const float* __restrict__ qn, const float* __restrict__ kn,
    const float* __restrict__ vb, const float* __restrict__ kb,
    float* __restrict__ u_g, u16t* __restrict__ w_bf, u16t* __restrict__ attn_bf,
    u16t* __restrict__ knT,
    const float* __restrict__ gW1, const float* __restrict__ Wo,
    u16t* __restrict__ W1hT, u16t* __restrict__ W1bT, u16t* __restrict__ WoT,
    float* __restrict__ wsum,
    const float* __restrict__ vbuf, const float* __restrict__ firs,
    const float* __restrict__ firl, float* __restrict__ fs, float* __restrict__ fl,
    u16t* __restrict__ brcat) {
  __shared__ __attribute__((aligned(16))) char smem[37376];
  int blk = blockIdx.x, t = threadIdx.x;
  if (blk < 256) {
    float (*KN)[260] = (float(*)[260])smem;          // 33280 B
    float (*Ms)[32] = (float(*)[32])(smem + 33280);  // 4096 B
    int i = blk & 31, bh = blk >> 5;
    int rbase = ((bh >> 2) * LL + i * 32) * NH + (bh & 3);
    i64 bhn = blk;
#pragma unroll
    for (int ii = 0; ii < 8; ii++) {
      int fid = t + ii * 256;
      int c = fid >> 6, dq = (fid & 63) << 2;
      *(float4*)&KN[c][dq] = *(const float4*)(kn + (i64)(rbase + c * NH) * 256 + dq);
    }
    __syncthreads();
    int c = t >> 3, e0 = (t & 7) * 4;
    const float* kbp = kb + (i64)(rbase + c * NH) * 256;
    const float* qp = qn + (i64)(rbase + c * NH) * 256;
    float am[4] = {0, 0, 0, 0}, aa[4] = {0, 0, 0, 0};
    for (int d = 0; d < 256; d += 4) {
      float4 kv = *(const float4*)(kbp + d);
      float4 qv = *(const float4*)(qp + d);
#pragma unroll
      for (int z = 0; z < 4; z++) {
        float4 nv = *(const float4*)&KN[e0 + z][d];
        am[z] += kv.x * nv.x + kv.y * nv.y + kv.z * nv.z + kv.w * nv.w;
        aa[z] += qv.x * nv.x + qv.y * nv.y + qv.z * nv.z + qv.w * nv.w;
      }
    }
    {
      uint2 o;
      u16t a0 = (e0 + 0 <= c) ? f2bf(aa[0]) : 0;
      u16t a1 = (e0 + 1 <= c) ? f2bf(aa[1]) : 0;
      u16t a2 = (e0 + 2 <= c) ? f2bf(aa[2]) : 0;
      u16t a3 = (e0 + 3 <= c) ? f2bf(aa[3]) : 0;
      o.x = pk2(a0, a1); o.y = pk2(a2, a3);
      *(uint2*)(attn_bf + bhn * 1024 + c * 32 + e0) = o;
    }
#pragma unroll
    for (int z = 0; z < 4; z++) {
      int e = e0 + z;
      Ms[c][e] = (e < c) ? am[z] : 0.0f;
    }
    __syncthreads();
    float uc[32], wc[32];
#pragma unroll
    for (int cc = 0; cc < 32; cc++) {
      float uval = vb[(i64)(rbase + cc * NH) * 256 + t];
      float wval = kb[(i64)(rbase + cc * NH) * 256 + t];
#pragma unroll
      for (int c2 = 0; c2 < cc; c2++) {
        float m = Ms[cc][c2];
        uval -= m * uc[c2];
        wval -= m * wc[c2];
      }
      uc[cc] = uval; wc[cc] = wval;
      u_g[(bhn * 32 + cc) * 256 + t] = uval;
      w_bf[(bhn * 32 + cc) * 256 + t] = f2bf(-wval);
    }
    int d = t;
    u16t o[32];
#pragma unroll
    for (int cc = 0; cc < 32; cc++) o[cc] = f2bf(KN[cc][d]);
#pragma unroll
    for (int z = 0; z < 4; z++) {
      uint4 vv;
      vv.x = pk2(o[z * 8 + 0], o[z * 8 + 1]);
      vv.y = pk2(o[z * 8 + 2], o[z * 8 + 3]);
      vv.z = pk2(o[z * 8 + 4], o[z * 8 + 5]);
      vv.w = pk2(o[z * 8 + 6], o[z * 8 + 7]);
      *(uint4*)(knT + (bhn * 256 + d) * 32 + z * 8) = vv;
    }
  } else if (blk < 2304) {
    float (*tile)[33] = (float(*)[33])smem;
    int pb = blk - 256;
    if (pb < 1024) {
      int which = pb >> 9, bi = pb & 511;
      const float* in = gW1 + (which ? (i64)4096 * 512 : 0);
      transcast_body(in, 512, which ? W1bT : W1hT, 1024, bi & 15, bi >> 4, tile);
    } else {
      int bi = pb - 1024;
      transcast_body(Wo, 1024, WoT, 1024, bi & 31, bi >> 5, tile);
    }
  } else if (blk < 2328) {
    int bi = blk - 2304;         // 24 blocks: 12 stats x 2 col-halves
    int s12 = bi >> 1, col = (bi & 1) * 256 + t;
    const float* p = gW1 + (i64)(1024 + s12 * 256) * 512 + col;
    float acc = 0.0f;
    for (int r = 0; r < 256; r++) acc += p[(i64)r * 512];
    wsum[s12 * 512 + col] = acc;
  } else {
    fir2_body(blk - 2328, vbuf, firs, firl, fs, fl, brcat);
  }
}

// ---------------- delta scan body (verbatim passing version) ----------------
#define SROW 264
struct ScanBuf {
  short8 m8[8];
  f32x4 uc4;
  short8 af;
  short8 kf[4];
};

__device__ void delta_scan_body(
    int blk,
    const u16t* __restrict__ wbf, const u16t* __restrict__ knT,
    const float* __restrict__ u_g, const u16t* __restrict__ qnbf,
    const u16t* __restrict__ attnbf,
    float* __restrict__ dlt, u16t* __restrict__ brcat,
    u16t* Sbf, u16t* Ubf) {
  int t = threadIdx.x, w = t >> 6, lane = t & 63;
  int l15 = lane & 15, quad = lane >> 4;
  int bh = blk & 7, jb = blk >> 3, j0 = jb * 16;
  int b_ = bh >> 2, h_ = bh & 3;
  bool isU = (w < 2);
  int wc = isU ? w : (w - 2);
  for (int idx = t; idx < 16 * SROW; idx += 256) Sbf[idx] = 0;
  f32x4 accS[4] = {};
  __syncthreads();
  __builtin_amdgcn_s_setprio(1);

  auto load_chunk = [&](int i, ScanBuf& B) {
    i64 bhn = (i64)bh * 32 + i;
    const u16t* mbase = isU
        ? wbf + (bhn * 32 + wc * 16 + l15) * 256 + quad * 8
        : qnbf + ((i64)bh * 1024 + i * 32 + wc * 16 + l15) * 256 + quad * 8;
#pragma unroll
    for (int kd = 0; kd < 8; kd++) B.m8[kd] = *(const short8*)(mbase + kd * 32);
    if (isU) {
      int cm = wc * 16 + quad * 4;
#pragma unroll
      for (int r = 0; r < 4; r++)
        B.uc4[r] = u_g[(bhn * 32 + cm + r) * 256 + j0 + l15];
    } else {
      B.af = *(const short8*)(attnbf + bhn * 1024 + (wc * 16 + l15) * 32 + quad * 8);
    }
#pragma unroll
    for (int dt = 0; dt < 4; dt++)
      B.kf[dt] = *(const short8*)(knT + (bhn * 256 + w * 64 + dt * 16 + l15) * 32 + quad * 8);
  };

  auto process = [&](int i, ScanBuf& B) {
    f32x4 zero = {};
    f32x4 ca = isU ? B.uc4 : zero;
    f32x4 cb = zero;
#pragma unroll
    for (int kd = 0; kd < 4; kd++) {
      short8 sfa = *(const short8*)&Sbf[l15 * SROW + kd * 32 + quad * 8];
      short8 sfb = *(const short8*)&Sbf[l15 * SROW + (kd + 4) * 32 + quad * 8];
      ca = MFMA_BF16(B.m8[kd], sfa, ca);
      cb = MFMA_BF16(B.m8[kd + 4], sfb, cb);
    }
    f32x4 cacc;
#pragma unroll
    for (int r = 0; r < 4; r++) cacc[r] = ca[r] + cb[r];
    if (isU) {
      int cm = wc * 16 + quad * 4;
      uint2 o;
      o.x = cvt_pk_bf16(cacc[0], cacc[1]);
      o.y = cvt_pk_bf16(cacc[2], cacc[3]);
      *(uint2*)&Ubf[l15 * 40 + cm] = o;
    }
    barrier_lds_only();
    short8 bu = *(const short8*)&Ubf[l15 * 40 + quad * 8];
    if (!isU) {
      cacc = MFMA_BF16(B.af, bu, cacc);
#pragma unroll
      for (int rg = 0; rg < 4; rg++) {
        int l = i * 32 + wc * 16 + quad * 4 + rg;
        i64 row = ((i64)b_ * 1024 + l) * 4 + h_;
        dlt[row * 256 + j0 + l15] = cacc[rg];
        brcat[row * 1024 + 512 + j0 + l15] = f2bf(cacc[rg]);
      }
    }
#pragma unroll
    for (int dt = 0; dt < 4; dt++) accS[dt] = MFMA_BF16(B.kf[dt], bu, accS[dt]);
#pragma unroll
    for (int dt = 0; dt < 4; dt++) {
      uint2 o;
      o.x = cvt_pk_bf16(accS[dt][0], accS[dt][1]);
      o.y = cvt_pk_bf16(accS[dt][2], accS[dt][3]);
      *(uint2*)&Sbf[l15 * SROW + w * 64 + dt * 16 + quad * 4] = o;
    }
    barrier_lds_only();
  };

  ScanBuf b0, b1;
  load_chunk(0, b0);
#pragma unroll 1
  for (int ii = 0; ii < 16; ii++) {
    int i = ii * 2;
    load_chunk(i + 1, b1);
    process(i, b0);
    if (ii < 15) load_chunk(i + 2, b0);
    process(i + 1, b1);
  }
  __builtin_amdgcn_s_setprio(0);
}

// ---------------- mega6: scan(128) + hbase gemm(64) + branchW partial(256) ----
__global__ __launch_bounds__(256) void mega6_kernel(
    const u16t* __restrict__ wbf, const u16t* __restrict__ knT,
    const float* __restrict__ u_g, const u16t* __restrict__ qnbf,
    const u16t* __restrict__ attnbf, float* __restrict__ dlt, u16t* __restrict__ brcat,
    const u16t* __restrict__ xbf, const u16t* __restrict__ W1hT,
    float* __restrict__ hbase,
    const u16t* __restrict__ W1bT, float* __restrict__ branchW) {
  __shared__ __attribute__((aligned(16))) char smem[32768];
  int blk = blockIdx.x;
  if (blk < 128) {
    u16t* Sbf = (u16t*)smem;
    u16t* Ubf = Sbf + 16 * SROW;
    delta_scan_body(blk, wbf, knT, u_g, qnbf, attnbf, dlt, brcat, Sbf, Ubf);
  } else if (blk < 192) {
    int bi = blk - 128;
    u16t* As = (u16t*)smem;
    u16t* Bs = As + 2 * 128 * 32;
    gemm_bt_body(xbf, W1hT, hbase, 1024, 512, (bi & 3) * 128, (bi >> 2) * 128, As, Bs);
  } else {
    int bi = blk - 192;
    u16t* As = (u16t*)smem;
    u16t* Bs = As + 2 * 128 * 32;
    int n0 = (bi & 3) * 128, m0 = (bi >> 2) * 128;
    f32x4 acc[4][4] = {};
    gemm_tiles_acc(brcat, W1bT, 1024, 768, 256, n0, m0, As, Bs, acc);
    gemm_tiles_acc(brcat, W1bT, 1024, 0, 512, n0, m0, As, Bs, acc);
    gemm_store(branchW, 512, n0, m0, acc, false);
  }
}

// ---------------- branchw_dlt: += brcat[:,512:768] @ W1bT[:,512:768]^T ----------------
__global__ __launch_bounds__(256) void branchw_dlt_kernel(
    const u16t* __restrict__ brcat, const u16t* __restrict__ W1bT,
    float* __restrict__ branchW) {
  __shared__ u16t As[2 * 128 * 32];
  __shared__ u16t Bs[2 * 128 * 32];
  int bi = blockIdx.x;
  int n0 = (bi & 3) * 128, m0 = (bi >> 2) * 128;
  f32x4 acc[4][4] = {};
  gemm_tiles_acc(brcat, W1bT, 1024, 512, 256, n0, m0, As, Bs, acc);
  gemm_store(branchW, 512, n0, m0, acc, true);
}

// ---------------- gate MLP tail + mix + RMS norm: WAVE-PER-ROW ----------------
__global__ __launch_bounds__(256) void gatemix_kernel(
    const float* __restrict__ hbase, const float* __restrict__ brW,
    const float* __restrict__ wsum,
    const float* __restrict__ gb1, const float* __restrict__ gW2,
    const float* __restrict__ gb2, const float* __restrict__ temp,
    const float* __restrict__ epsf,
    const float* __restrict__ fs, const float* __restrict__ fl,
    const float* __restrict__ dlt, const float* __restrict__ v,
    const float* __restrict__ onw, u16t* __restrict__ out) {
  int t = threadIdx.x, lane = t & 63, wv = t >> 6;
  int row = blockIdx.x * 4 + wv;      // (b*1024+l)*4+h
  int bl = row >> 2, h = row & 3;
  i64 base = (i64)row * 256 + lane * 4;
  float4 vfs = *(const float4*)(fs + base);
  float4 vfl = *(const float4*)(fl + base);
  float4 vdl = *(const float4*)(dlt + base);
  float4 vvv = *(const float4*)(v + base);
  float r8[8];
  r8[0] = vfs.x + vfs.y + vfs.z + vfs.w;
  r8[1] = vfs.x * vfs.x + vfs.y * vfs.y + vfs.z * vfs.z + vfs.w * vfs.w;
  r8[2] = vfl.x + vfl.y + vfl.z + vfl.w;
  r8[3] = vfl.x * vfl.x + vfl.y * vfl.y + vfl.z * vfl.z + vfl.w * vfl.w;
  r8[4] = vdl.x + vdl.y + vdl.z + vdl.w;
  r8[5] = vdl.x * vdl.x + vdl.y * vdl.y + vdl.z * vdl.z + vdl.w * vdl.w;
  r8[6] = vvv.x + vvv.y + vvv.z + vvv.w;
  r8[7] = vvv.x * vvv.x + vvv.y * vvv.y + vvv.z * vvv.z + vvv.w * vvv.w;
#pragma unroll
  for (int off = 1; off < 64; off <<= 1) {
#pragma unroll
    for (int i = 0; i < 8; i++) r8[i] += __shfl_xor(r8[i], off);
  }
  float m4[4];
  m4[0] = fmaxf(fmaxf(vfs.x, vfs.y), fmaxf(vfs.z, vfs.w));
  m4[1] = fmaxf(fmaxf(vfl.x, vfl.y), fmaxf(vfl.z, vfl.w));
  m4[2] = fmaxf(fmaxf(vdl.x, vdl.y), fmaxf(vdl.z, vdl.w));
  m4[3] = fmaxf(fmaxf(vvv.x, vvv.y), fmaxf(vvv.z, vvv.w));
#pragma unroll
  for (int off = 1; off < 64; off <<= 1) {
#pragma unroll
    for (int i = 0; i < 4; i++) m4[i] = fmaxf(m4[i], __shfl_xor(m4[i], off));
  }
  float st[12];
#pragma unroll
  for (int p = 0; p < 4; p++) {
    st[p * 3 + 0] = r8[p * 2] * (1.0f / 256.0f);
    st[p * 3 + 1] = sqrtf(fmaxf(r8[p * 2 + 1] * (1.0f / 256.0f), 1e-8f));
    st[p * 3 + 2] = m4[p];
  }
  float lg[4] = {0, 0, 0, 0};
#pragma unroll
  for (int jj = 0; jj < 8; jj++) {
    int o = jj * 64 + lane;
    float hm = hbase[(i64)bl * 512 + o] + brW[(i64)row * 512 + o] + gb1[o];
#pragma unroll
    for (int s = 0; s < 12; s++) hm += st[s] * wsum[s * 512 + o];
    float ge = 0.5f * hm * (1.0f + erff(hm * 0.70710678118654752f));
    float4 w2 = *(const float4*)(gW2 + o * 4);
    lg[0] += ge * w2.x; lg[1] += ge * w2.y; lg[2] += ge * w2.z; lg[3] += ge * w2.w;
  }
#pragma unroll
  for (int off = 1; off < 64; off <<= 1) {
#pragma unroll
    for (int i = 0; i < 4; i++) lg[i] += __shfl_xor(lg[i], off);
  }
  float tt = fminf(fmaxf(temp[h], 0.2f), 10.0f);
  float l0 = (lg[0] + gb2[0]) / tt;
  float l1 = (lg[1] + gb2[1]) / tt;
  float l2 = (lg[2] + gb2[2]) / tt;
  float l3 = (lg[3] + gb2[3]) / tt;
  float m = fmaxf(fmaxf(l0, l1), fmaxf(l2, l3));
  float e0 = expf(l0 - m), e1 = expf(l1 - m), e2 = expf(l2 - m), e3 = expf(l3 - m);
  float ssum = e0 + e1 + e2 + e3;
  float w0 = e0 / ssum, w1 = e1 / ssum, w2 = e2 / ssum, w3 = e3 / ssum;
  w0 = fmaxf(w0, fminf(fmaxf(epsf[h * 4 + 0], 1e-7f), 0.1f));
  w1 = fmaxf(w1, fminf(fmaxf(epsf[h * 4 + 1], 1e-7f), 0.1f));
  w2 = fmaxf(w2, fminf(fmaxf(epsf[h * 4 + 2], 1e-7f), 0.1f));
  w3 = fmaxf(w3, fminf(fmaxf(epsf[h * 4 + 3], 1e-7f), 0.1f));
  float s2 = w0 + w1 + w2 + w3;
  float g0 = w0 / s2, g1 = w1 / s2, g2 = w2 / s2, g3 = w3 / s2;
  float4 o4;
  o4.x = g0 * vfs.x + g1 * vfl.x + g2 * vdl.x + g3 * vvv.x;
  o4.y = g0 * vfs.y + g1 * vfl.y + g2 * vdl.y + g3 * vvv.y;
  o4.z = g0 * vfs.z + g1 * vfl.z + g2 * vdl.z + g3 * vvv.z;
  o4.w = g0 * vfs.w + g1 * vfl.w + g2 * vdl.w + g3 * vvv.w;
  float ss = o4.x * o4.x + o4.y * o4.y + o4.z * o4.z + o4.w * o4.w;
#pragma unroll
  for (int off = 1; off < 64; off <<= 1) ss += __shfl_xor(ss, off);
  float scale = rsqrtf(ss * (1.0f / 256.0f) + 1e-5f);
  float4 ow4 = *(const float4*)(onw + lane * 4);
  uint2 ow;
  ow.x = cvt_pk_bf16(o4.x * scale * ow4.x, o4.y * scale * ow4.y);
  ow.y = cvt_pk_bf16(o4.z * scale * ow4.z, o4.w * scale * ow4.w);
  *(uint2*)(out + (i64)bl * 1024 + h * 256 + lane * 4) = ow;
}

extern "C" void kernel_launch(void* const* d_in, const int* in_sizes, int n_in,
                              void* d_out, int out_size, void* d_ws, size_t ws_size,
                              hipStream_t stream) {
  (void)in_sizes; (void)n_in; (void)out_size; (void)ws_size;
  const float* x    = (const float*)d_in[0];
  const float* Wq   = (const float*)d_in[1];
  const float* Wk   = (const float*)d_in[2];
  const float* Wv   = (const float*)d_in[3];
  const float* Wb   = (const float*)d_in[4];
  const float* qcw  = (const float*)d_in[5];
  const float* kcw  = (const float*)d_in[6];
  const float* vcw  = (const float*)d_in[7];
  const float* gW1  = (const float*)d_in[8];
  const float* gb1  = (const float*)d_in[9];
  const float* gW2  = (const float*)d_in[10];
  const float* gb2  = (const float*)d_in[11];
  const float* temp = (const float*)d_in[12];
  const float* epsf = (const float*)d_in[13];
  const float* onw  = (const float*)d_in[14];
  const float* Wo   = (const float*)d_in[15];
  const float* firs = (const float*)d_in[16];
  const float* firl = (const float*)d_in[17];
  float* out = (float*)d_out;

  float* ws = (float*)d_ws;
  // ---- workspace map (float offsets) ----
  float* qkv_pre  = ws + 0;                       // 2048*3072 fp32 (dead after conv)
  float* branchW  = ws + 0;                       // 8192*512 fp32 (step 5+)
  float* hbase    = ws + 4194304;                 // 2048*512 fp32 (step 5+)
  u16t*  W1hT     = (u16t*)(ws + 5242880);        // 512x1024 bf16 (step 4+)
  u16t*  W1bT     = (u16t*)(ws + 5505024);        // 512x1024 bf16
  u16t*  WoT      = (u16t*)(ws + 5767168);        // 1024x1024 bf16
  u16t*  brcat    = (u16t*)(ws + 6291456);        // 8192*1024 bf16
  float* qn       = ws + 10485760;                // 2048*1024 fp32 (conv_fused+)
  float* kn       = ws + 12582912;
  float* vbuf     = ws + 14680064;
  float* vb       = ws + 16777216;                // dead after phaseA3
  u16t*  omix_bf  = (u16t*)(ws + 16777216);       // gatemix+ (2048*1024 bf16)
  float* kb       = ws + 18874368;                // dead after phaseA3
  float* dlt      = ws + 18874368;                // scan output
  float* u_g      = ws + 20971520;
  u16t*  w_bf     = (u16t*)(ws + 23068672);
  u16t*  qn_bf    = (u16t*)(ws + 24117248);
  u16t*  knT      = (u16t*)(ws + 25165824);
  u16t*  attn_bf  = (u16t*)(ws + 26214400);
  float* fs       = ws + 26345472;
  float* fl       = ws + 28442624;
  u16t*  xbf      = (u16t*)(ws + 30539776);
  u16t*  WqkvT    = (u16t*)(ws + 31588352);
  float* betab    = ws + 33161216;                // 8192 fp32
  float* wsum     = ws + 33267712;

  // 1) prep: QKV weight transpose + x cast + beta
  prep_kernel<<<7168, 256, 0, stream>>>(Wq, Wk, Wv, x, Wb, WqkvT, xbf, betab);
  // 2) QKV GEMM (2-phase dbuf global_load_lds staging)
  gemm_bt_kernel<<<dim3(24, 16), 256, 0, stream>>>(xbf, WqkvT, qkv_pre, 1024, 3072);
  // 3) conv+silu fused with l2norm/beta-scale (preprocess deleted); kills qkv_pre
  conv_fused_kernel<<<6144, 256, 0, stream>>>(qkv_pre, qcw, kcw, vcw, betab,
                                              qn, kn, vbuf, vb, kb, qn_bf, brcat);
  // 4) phaseA3: UT-transform + W1/Wo transposes + wsum + FIR
  phaseA3_kernel<<<2840, 256, 0, stream>>>(qn, kn, vb, kb, u_g, w_bf, attn_bf, knT,
                                           gW1, Wo, W1hT, W1bT, WoT, wsum,
                                           vbuf, firs, firl, fs, fl, brcat);
  // 5) mega6: scan + hbase GEMM + branchW partial (K 768-1024 and 0-512)
  mega6_kernel<<<448, 256, 0, stream>>>(w_bf, knT, u_g, qn_bf, attn_bf, dlt, brcat,
                                        xbf, W1hT, hbase, W1bT, branchW);
  // 6) branchW dlt K-block (512-768), accumulate
  branchw_dlt_kernel<<<256, 256, 0, stream>>>(brcat, W1bT, branchW);
  // 7) gate tail + mix + RMS (wave-per-row, no barriers)
  gatemix_kernel<<<2048, 256, 0, stream>>>(hbase, branchW, wsum, gb1, gW2, gb2,
                                           temp, epsf, fs, fl, dlt, vbuf, onw, omix_bf);
  // 8) final projection
  gemm_bt_kernel<<<dim3(8, 16), 256, 0, stream>>>(omix_bf, WoT, out, 1024, 1024);
}